// Round 13
// baseline (6766.799 us; speedup 1.0000x reference)
//
#include <hip/hip_runtime.h>
#include <math.h>

#define NB 16      // batch
#define NN 128     // spatial
#define WC 64      // width / channels
#define DD 64      // D1=D2
#define NP 66      // D + BW - 1

typedef float v4f __attribute__((ext_vector_type(4)));
typedef unsigned int u32;

__device__ __forceinline__ float gelu_f(float x) {
    return 0.5f * x * (1.0f + erff(x * 0.70710678118654752f));
}

// width-16 global->LDS direct copy (dest = wave-uniform base + lane*16)
__device__ __forceinline__ void gload16(const float* g, float* l) {
    __builtin_amdgcn_global_load_lds(
        (const __attribute__((address_space(1))) u32*)g,
        (__attribute__((address_space(3))) u32*)l, 16, 0, 0);
}

// ---------------- DST matrix ----------------
__global__ void k_dst(float* __restrict__ S) {
    int idx = blockIdx.x * 256 + threadIdx.x;   // 16384
    int k = idx >> 7, j = idx & 127;
    double arg = 3.14159265358979323846 * (double)((k + 1) * (j + 1)) / 129.0;
    S[idx] = (float)(sqrt(2.0 / 129.0) * sin(arg));
}

// ---------------- transpose input (B,N,N,3) -> (B,64ch,N,N) ch0..2 ----------------
__global__ void k_tin(const float* __restrict__ in, float* __restrict__ xc) {
    int idx = blockIdx.x * 256 + threadIdx.x;   // 16*3*16384
    int j = idx & 127;
    int i = (idx >> 7) & 127;
    int t = idx >> 14;           // b*3 + c
    int b = t / 3, c = t - b * 3;
    xc[(((size_t)b * WC + c) << 14) + i * 128 + j] =
        in[((size_t)(b * 128 + i) * 128 + j) * 3 + c];
}

// ---------------- forward transform, compact 66x(68-padded) output ----------------
// (round-2 compute; output rows padded to 68 floats, channel stride 4488, so
//  mix6's width-16 global_load_lds sources are all 16B-aligned and LDS-linear)
__global__ __launch_bounds__(256) void k_tfwd66(const float* __restrict__ Xg,
                                                float* __restrict__ Yc,
                                                const float* __restrict__ Sg,
                                                int Cact) {
    __shared__ float sSt[80 * 132];
    __shared__ float sU[66 * 132];
    int bid = blockIdx.x;
    int b = bid / Cact, c = bid - b * Cact;
    const float* X = Xg + (((size_t)b * WC + c) << 14);
    int tid = threadIdx.x;
    int tx = tid & 15, ty = tid >> 4;
    for (int l = tid; l < 80 * 128; l += 256)
        sSt[(l >> 7) * 132 + (l & 127)] = Sg[l];
    float acc[8][5];
#pragma unroll
    for (int r = 0; r < 8; ++r)
#pragma unroll
        for (int q = 0; q < 5; ++q) acc[r][q] = 0.f;
    for (int jh = 0; jh < 2; ++jh) {
        __syncthreads();
        for (int l = tid; l < 8192; l += 256)
            sU[(l >> 6) * 68 + (l & 63)] = X[((l >> 6) << 7) + jh * 64 + (l & 63)];
        __syncthreads();
        for (int jj = 0; jj < 64; jj += 4) {
            float4 xv[8], sv[5];
#pragma unroll
            for (int r = 0; r < 8; ++r)
                xv[r] = *(const float4*)&sU[(ty + 16 * r) * 68 + jj];
#pragma unroll
            for (int q = 0; q < 5; ++q)
                sv[q] = *(const float4*)&sSt[(tx + 16 * q) * 132 + jh * 64 + jj];
#pragma unroll
            for (int r = 0; r < 8; ++r)
#pragma unroll
                for (int q = 0; q < 5; ++q) {
                    acc[r][q] += xv[r].x * sv[q].x;
                    acc[r][q] += xv[r].y * sv[q].y;
                    acc[r][q] += xv[r].z * sv[q].z;
                    acc[r][q] += xv[r].w * sv[q].w;
                }
        }
    }
    __syncthreads();
#pragma unroll
    for (int q = 0; q < 5; ++q) {
        int k = tx + 16 * q;
        if (k < 66) {
#pragma unroll
            for (int r = 0; r < 8; ++r)
                sU[k * 132 + ty + 16 * r] = acc[r][q];
        }
    }
    __syncthreads();
    float a2[5][5];
#pragma unroll
    for (int r = 0; r < 5; ++r)
#pragma unroll
        for (int q = 0; q < 5; ++q) a2[r][q] = 0.f;
    for (int i0 = 0; i0 < 128; i0 += 4) {
        float4 sv[5], tv[5];
#pragma unroll
        for (int r = 0; r < 5; ++r)
            sv[r] = *(const float4*)&sSt[(ty + 16 * r) * 132 + i0];
#pragma unroll
        for (int q = 0; q < 5; ++q) {
            int m = tx + 16 * q;
            if (m < 66) tv[q] = *(const float4*)&sU[m * 132 + i0];
            else { tv[q].x = 0.f; tv[q].y = 0.f; tv[q].z = 0.f; tv[q].w = 0.f; }
        }
#pragma unroll
        for (int r = 0; r < 5; ++r)
#pragma unroll
            for (int q = 0; q < 5; ++q) {
                a2[r][q] += sv[r].x * tv[q].x;
                a2[r][q] += sv[r].y * tv[q].y;
                a2[r][q] += sv[r].z * tv[q].z;
                a2[r][q] += sv[r].w * tv[q].w;
            }
    }
    float* Y = Yc + (size_t)(b * WC + c) * 4488;    // 66 rows x 68-stride
#pragma unroll
    for (int r = 0; r < 5; ++r) {
        int kk = ty + 16 * r;
        if (kk < 66) {
#pragma unroll
            for (int q = 0; q < 5; ++q) {
                int m = tx + 16 * q;
                if (m < 66) Y[kk * 68 + m] = a2[r][q];
            }
        }
    }
}

// ---------------- inverse transform + partial-sum + optional gelu/ch-offset ----------
// v5: DST parity fold on OUTPUT cols (stage 1) and OUTPUT rows (stage 2).
// FMA 6144->3072, LDS reads 704->512, sS 16KB -> 3 blocks/CU. (round-10 win)
__global__ __launch_bounds__(256, 3) void k_tinv(const float* __restrict__ Op,
                                                 float* __restrict__ Yg,
                                                 const float* __restrict__ Sg,
                                                 int Cact, int ncc, int ch_off, int do_gelu) {
    __shared__ float sS[64 * 64];      // S rows 0..63, cols 0..63 (16 KB)
    __shared__ float sXT[64 * 132];    // union: X (stride 66) then T (stride 132)
    int bid = blockIdx.x;
    int b = bid / Cact, c = bid - b * Cact;
    const float* X = Op + ((size_t)(b * WC + c) << 12);
    const size_t cstride = (size_t)NB * WC * 4096;
    float* Y = Yg + (((size_t)b * WC + c + ch_off) << 14);
    int tid = threadIdx.x;
    for (int l = tid; l < 4096; l += 256)
        sS[l] = Sg[((l >> 6) << 7) + (l & 63)];
    for (int l = tid; l < 4096; l += 256) {
        int r = l >> 6, q = l & 63;
        float v = X[l];
        for (int cc = 1; cc < ncc; ++cc) v += X[cc * cstride + l];
        sXT[r * 66 + q] = v;            // stride 66: b64-aligned pair reads later
    }
    __syncthreads();
    int cg = tid & 7;
    int rg = tid >> 3;                  // 0..31
    // ---- stage 1 (col-fold): P/M over even/odd j, cols c = cg*4+32m' (m'<2) ----
    v4f aP[2][2], aM[2][2];
#pragma unroll
    for (int r = 0; r < 2; ++r)
#pragma unroll
        for (int m = 0; m < 2; ++m) {
            aP[r][m].x = 0.f; aP[r][m].y = 0.f; aP[r][m].z = 0.f; aP[r][m].w = 0.f;
            aM[r][m].x = 0.f; aM[r][m].y = 0.f; aM[r][m].z = 0.f; aM[r][m].w = 0.f;
        }
    for (int jp = 0; jp < 32; ++jp) {
        float2 x0 = *(const float2*)&sXT[(rg * 2 + 0) * 66 + 2 * jp];
        float2 x1 = *(const float2*)&sXT[(rg * 2 + 1) * 66 + 2 * jp];
#pragma unroll
        for (int m = 0; m < 2; ++m) {
            v4f se = *(const v4f*)&sS[(2 * jp) * 64 + cg * 4 + 32 * m];
            v4f so = *(const v4f*)&sS[(2 * jp + 1) * 64 + cg * 4 + 32 * m];
            aP[0][m] += se * x0.x;  aM[0][m] += so * x0.y;
            aP[1][m] += se * x1.x;  aM[1][m] += so * x1.y;
        }
    }
    __syncthreads();                    // all X reads done; reuse buffer for T
#pragma unroll
    for (int r = 0; r < 2; ++r)
#pragma unroll
        for (int m = 0; m < 2; ++m) {
            v4f tlo = aP[r][m] + aM[r][m];
            v4f td  = aP[r][m] - aM[r][m];
            v4f thi; thi.x = td.w; thi.y = td.z; thi.z = td.y; thi.w = td.x;
            int row = rg * 2 + r;
            *(v4f*)&sXT[row * 132 + cg * 4 + 32 * m] = tlo;
            *(v4f*)&sXT[row * 132 + 124 - cg * 4 - 32 * m] = thi;
        }
    __syncthreads();
    // ---- stage 2 (row-fold): P/M over even/odd i; rows rg*2+r and 127-(rg*2+r) ----
    v4f p2[2][4], m2[2][4];
#pragma unroll
    for (int r = 0; r < 2; ++r)
#pragma unroll
        for (int m = 0; m < 4; ++m) {
            p2[r][m].x = 0.f; p2[r][m].y = 0.f; p2[r][m].z = 0.f; p2[r][m].w = 0.f;
            m2[r][m].x = 0.f; m2[r][m].y = 0.f; m2[r][m].z = 0.f; m2[r][m].w = 0.f;
        }
    for (int ip = 0; ip < 32; ++ip) {
        float2 sve = *(const float2*)&sS[(2 * ip) * 64 + rg * 2];
        float2 svo = *(const float2*)&sS[(2 * ip + 1) * 64 + rg * 2];
#pragma unroll
        for (int m = 0; m < 4; ++m) {
            v4f te = *(const v4f*)&sXT[(2 * ip) * 132 + cg * 4 + 32 * m];
            v4f to = *(const v4f*)&sXT[(2 * ip + 1) * 132 + cg * 4 + 32 * m];
            p2[0][m] += te * sve.x;  p2[1][m] += te * sve.y;
            m2[0][m] += to * svo.x;  m2[1][m] += to * svo.y;
        }
    }
#pragma unroll
    for (int r = 0; r < 2; ++r) {
        int rlo = rg * 2 + r, rhi = 127 - rlo;
#pragma unroll
        for (int m = 0; m < 4; ++m) {
            v4f ylo = p2[r][m] + m2[r][m];
            v4f yhi = p2[r][m] - m2[r][m];
            if (do_gelu) {
                ylo.x = gelu_f(ylo.x); ylo.y = gelu_f(ylo.y);
                ylo.z = gelu_f(ylo.z); ylo.w = gelu_f(ylo.w);
                yhi.x = gelu_f(yhi.x); yhi.y = gelu_f(yhi.y);
                yhi.z = gelu_f(yhi.z); yhi.w = gelu_f(yhi.w);
            }
            *(v4f*)&Y[rlo * 128 + cg * 4 + 32 * m] = ylo;
            *(v4f*)&Y[rhi * 128 + cg * 4 + 32 * m] = yhi;
        }
    }
}

// ---------------- spectral channel mixing v7 ----------------
// 2 ocs per thread (A-LDS-reads amortized 2x — the measured mix6 bottleneck),
// NO bbh split (every thread's 18 weight loads unique: round-8's bbh twins
// silently doubled weight traffic). acc[2][16][4]=128 + wv dbuf 144 ~ 300 live
// VGPR: legal under __launch_bounds__(256,1) (gfx950 unified RF: ~512/wave,
// no spill through ~450 [m08/m24]; excess parks in AGPRs). 1 block/CU; weight
// stream (604 MB/layer) becomes the binding constraint (~96 us/layer floor).
// FMA order per output identical to v4 -> absmax fingerprint 1.2207e-4 exact.
// [If VGPR_Count reports a clamp + mix6 >1ms: revert to v4, mix6 closed.]
__global__ __launch_bounds__(256, 1) void k_mix6(const float* __restrict__ Ac,
                                                 const float* __restrict__ Wt,
                                                 float* __restrict__ Op,
                                                 int Cin, int Cout, int cper) {
    __shared__ __align__(16) float sa[2][16 * 4 * 68];   // 2 x 4352 floats
    int bx = blockIdx.x;         // 0..31 (x pair)
    int ocb = blockIdx.y;        // 0..3
    int ccb = blockIdx.z;
    int c0 = ccb * cper;
    int c1 = c0 + cper; if (c1 > Cin) c1 = Cin;
    int tid = threadIdx.x;
    int yq = tid & 15, ocl = (tid >> 4) & 7, xh = tid >> 7;
    int x = bx * 2 + xh;
    int oc0 = ocb * 16 + ocl;
    int oc1 = oc0 + 8;
    bool ok0 = oc0 < Cout, ok1 = oc1 < Cout;
    v4f z4; z4.x = 0.f; z4.y = 0.f; z4.z = 0.f; z4.w = 0.f;

    const size_t wstep = (size_t)Cout * 4096;
    const float* wb0 = Wt + (size_t)(ok0 ? oc0 : 0) * 4096 + x * 64 + (yq << 2);
    const float* wb1 = Wt + (size_t)(ok1 ? oc1 : 0) * 4096 + x * 64 + (yq << 2);

    // gload16 slots: LDS v4f v = tid + 256k, float f = 4v; window [bb][4][68]
    // maps to global channel offset bx*136 + (f % 272) within batch bb = f/272.
    int gbase[5];
#pragma unroll
    for (int k = 0; k < 5; ++k) {
        int f = 4 * tid + 1024 * k;
        int fv = (f < 4352) ? f : 0;
        int bb = fv / 272; int off = fv - bb * 272;
        gbase[k] = bb * (WC * 4488) + bx * 136 + off;
    }

    float acc[2][16][4];
#pragma unroll
    for (int o2 = 0; o2 < 2; ++o2)
#pragma unroll
        for (int bb = 0; bb < 16; ++bb)
#pragma unroll
            for (int k = 0; k < 4; ++k) acc[o2][bb][k] = 0.f;

    // ---- prologue: stage A[c0] into sa[0]; weights for c0 (both ocs) ----
    {
        const float* src = Ac + (size_t)c0 * 4488;
#pragma unroll
        for (int k = 0; k < 4; ++k)
            gload16(src + gbase[k], &sa[0][4 * tid + 1024 * k]);
        if (tid < 64) gload16(src + gbase[4], &sa[0][4 * tid + 4096]);
    }
    v4f wvA[2][9];
#pragma unroll
    for (int t = 0; t < 9; ++t) {
        wvA[0][t] = ok0 ? __builtin_nontemporal_load(
                              (const v4f*)(wb0 + ((size_t)c0 * 9 + t) * wstep)) : z4;
        wvA[1][t] = ok1 ? __builtin_nontemporal_load(
                              (const v4f*)(wb1 + ((size_t)c0 * 9 + t) * wstep)) : z4;
    }
    __syncthreads();

    int cur = 0;
    for (int c = c0; c < c1; ++c) {
        bool hn = (c + 1) < c1;          // block-uniform
        v4f wvN[2][9];
        if (hn) {
            float* dst = sa[cur ^ 1];
            const float* src = Ac + (size_t)(c + 1) * 4488;
#pragma unroll
            for (int k = 0; k < 4; ++k)
                gload16(src + gbase[k], dst + 4 * tid + 1024 * k);
            if (tid < 64) gload16(src + gbase[4], dst + 4 * tid + 4096);
#pragma unroll
            for (int t = 0; t < 9; ++t) {
                wvN[0][t] = ok0 ? __builtin_nontemporal_load(
                                      (const v4f*)(wb0 + ((size_t)(c + 1) * 9 + t) * wstep)) : z4;
                wvN[1][t] = ok1 ? __builtin_nontemporal_load(
                                      (const v4f*)(wb1 + ((size_t)(c + 1) * 9 + t) * wstep)) : z4;
            }
        }
        const float* sab = sa[cur];
#pragma unroll
        for (int pi = 0; pi < 3; ++pi) {
#pragma unroll
            for (int bb = 0; bb < 16; ++bb) {
                const float* sp = &sab[(bb * 4 + xh + pi) * 68 + (yq << 2)];
                float4 s0 = *(const float4*)sp;
                float2 s1 = *(const float2*)(sp + 4);
                float sv[6] = {s0.x, s0.y, s0.z, s0.w, s1.x, s1.y};
#pragma unroll
                for (int k = 0; k < 4; ++k)
#pragma unroll
                    for (int pj = 0; pj < 3; ++pj) {
                        acc[0][bb][k] = fmaf(sv[k + pj], wvA[0][pi * 3 + pj][k], acc[0][bb][k]);
                        acc[1][bb][k] = fmaf(sv[k + pj], wvA[1][pi * 3 + pj][k], acc[1][bb][k]);
                    }
            }
        }
        if (hn) {
            __syncthreads();             // drains gload_lds (vmcnt) + read hazard
#pragma unroll
            for (int t = 0; t < 9; ++t) {
                wvA[0][t] = wvN[0][t];
                wvA[1][t] = wvN[1][t];
            }
            cur ^= 1;
        }
    }

    float* Opc = Op + (size_t)ccb * ((size_t)NB * WC * 4096);
#pragma unroll
    for (int o2 = 0; o2 < 2; ++o2) {
        bool ok = o2 ? ok1 : ok0;
        int oc = o2 ? oc1 : oc0;
        if (ok) {
#pragma unroll
            for (int bb = 0; bb < 16; ++bb) {
                float4 o4;
                o4.x = acc[o2][bb][0]; o4.y = acc[o2][bb][1];
                o4.z = acc[o2][bb][2]; o4.w = acc[o2][bb][3];
                *(float4*)&Opc[(((size_t)bb * WC + oc) << 12) + x * 64 + (yq << 2)] = o4;
            }
        }
    }
}

// ---------------- block update: xc = xc + gelu(conv1x1(xc)+bias + t1) ----------------
// v2: x-row hoisted to 64 VGPRs, LDS-staged weights read as broadcast b128
// (measured faster than wave-uniform global loads — round 4).
__global__ __launch_bounds__(256) void k_blockup(float* __restrict__ xc,
                                                 const float* __restrict__ sp,
                                                 const float* __restrict__ wmat,
                                                 const float* __restrict__ bias) {
    __shared__ float sw[64 * 64];
    __shared__ float sx[128 * 65];
    __shared__ float sb[64];
    int bi = blockIdx.x;          // b*128 + i
    int b = bi >> 7, i = bi & 127;
    int tid = threadIdx.x;
    for (int l = tid; l < 4096; l += 256) sw[l] = wmat[l];
    if (tid < 64) sb[tid] = bias[tid];
    for (int l = tid; l < 8192; l += 256) {
        int c = l >> 7, j = l & 127;
        sx[j * 65 + c] = xc[(((size_t)b * WC + c) << 14) + i * 128 + j];
    }
    __syncthreads();
    int j = tid & 127, h = tid >> 7;
    float xr[64];
#pragma unroll
    for (int c = 0; c < 64; ++c) xr[c] = sx[j * 65 + c];
#pragma unroll 2
    for (int o = 0; o < 32; ++o) {
        int oc = h * 32 + o;
        float a = sb[oc];
#pragma unroll
        for (int c4 = 0; c4 < 16; ++c4) {
            v4f w4 = *(const v4f*)&sw[oc * 64 + c4 * 4];
            a = fmaf(xr[c4 * 4 + 0], w4.x, a);
            a = fmaf(xr[c4 * 4 + 1], w4.y, a);
            a = fmaf(xr[c4 * 4 + 2], w4.z, a);
            a = fmaf(xr[c4 * 4 + 3], w4.w, a);
        }
        size_t gi = (((size_t)b * WC + oc) << 14) + i * 128 + j;
        float v = a + sp[gi];
        xc[gi] = sx[j * 65 + oc] + gelu_f(v);
    }
}

// ---------------- final MLP: out = (gelu(x@W1+b1))@W2 + b2 ----------------
// v2: x-row in registers, W1 staged transposed so the inner read is broadcast b128.
__global__ __launch_bounds__(256) void k_fc(const float* __restrict__ xc,
                                            const float* __restrict__ W1,
                                            const float* __restrict__ b1,
                                            const float* __restrict__ W2,
                                            const float* __restrict__ b2,
                                            float* __restrict__ out) {
    __shared__ float sW1T[128 * 68];   // [oo][c], 16B-aligned rows
    __shared__ float sx[128 * 65];
    __shared__ float sW2[128];
    __shared__ float sb1[128];
    __shared__ float spart[256];
    int bi = blockIdx.x; int b = bi >> 7, i = bi & 127;
    int tid = threadIdx.x;
    for (int l = tid; l < 8192; l += 256) {
        int c = l >> 7, oo = l & 127;
        sW1T[oo * 68 + c] = W1[l];
    }
    if (tid < 128) { sW2[tid] = W2[tid]; sb1[tid] = b1[tid]; }
    for (int l = tid; l < 8192; l += 256) {
        int c = l >> 7, j = l & 127;
        sx[j * 65 + c] = xc[(((size_t)b * WC + c) << 14) + i * 128 + j];
    }
    __syncthreads();
    int j = tid & 127, h = tid >> 7;
    float xr[64];
#pragma unroll
    for (int c = 0; c < 64; ++c) xr[c] = sx[j * 65 + c];
    float part = 0.f;
#pragma unroll 2
    for (int o = 0; o < 64; ++o) {
        int oo = h * 64 + o;
        float a = sb1[oo];
#pragma unroll
        for (int c4 = 0; c4 < 16; ++c4) {
            v4f w4 = *(const v4f*)&sW1T[oo * 68 + c4 * 4];
            a = fmaf(xr[c4 * 4 + 0], w4.x, a);
            a = fmaf(xr[c4 * 4 + 1], w4.y, a);
            a = fmaf(xr[c4 * 4 + 2], w4.z, a);
            a = fmaf(xr[c4 * 4 + 3], w4.w, a);
        }
        part += gelu_f(a) * sW2[oo];
    }
    spart[j * 2 + h] = part;
    __syncthreads();
    if (h == 0) out[(size_t)bi * 128 + j] = spart[j * 2] + spart[j * 2 + 1] + b2[0];
}

extern "C" void kernel_launch(void* const* d_in, const int* in_sizes, int n_in,
                              void* d_out, int out_size, void* d_ws, size_t ws_size,
                              hipStream_t stream) {
    (void)in_sizes; (void)n_in; (void)out_size; (void)ws_size;
    const float* x_in    = (const float*)d_in[0];
    const float* convl_w = (const float*)d_in[1];
    const float* conv_w[4] = {(const float*)d_in[2], (const float*)d_in[3],
                              (const float*)d_in[4], (const float*)d_in[5]};
    const float* ww[4] = {(const float*)d_in[6], (const float*)d_in[8],
                          (const float*)d_in[10], (const float*)d_in[12]};
    const float* wb[4] = {(const float*)d_in[7], (const float*)d_in[9],
                          (const float*)d_in[11], (const float*)d_in[13]};
    const float* fc1w = (const float*)d_in[14];
    const float* fc1b = (const float*)d_in[15];
    const float* fc2w = (const float*)d_in[16];
    const float* fc2b = (const float*)d_in[17];
    float* out = (float*)d_out;

    float* S   = (float*)d_ws;                       // 16384
    float* xc  = S + 16384;                          // 16.8M floats
    float* t1  = xc + (size_t)NB * WC * 16384;       // 16.8M floats
    float* tA  = t1 + (size_t)NB * WC * 16384;       // 4.60M floats (66x68-padded)
    float* Op  = tA + (size_t)NB * WC * 4488;        // 2 x 4.19M partials

    k_dst<<<64, 256, 0, stream>>>(S);
    k_tin<<<3072, 256, 0, stream>>>(x_in, xc);

    // lifting: u3 -> wswano(3 -> 61) -> gelu -> channels 3..63
    k_tfwd66<<<NB * 3, 256, 0, stream>>>(xc, tA, S, 3);
    k_mix6<<<dim3(32, 4, 1), 256, 0, stream>>>(tA, convl_w, Op, 3, 61, 3);
    k_tinv<<<NB * 61, 256, 0, stream>>>(Op, xc, S, 61, 1, 3, 1);

    for (int L = 0; L < 4; ++L) {
        k_tfwd66<<<NB * WC, 256, 0, stream>>>(xc, tA, S, WC);
        k_mix6<<<dim3(32, 4, 2), 256, 0, stream>>>(tA, conv_w[L], Op, WC, WC, 32);
        k_tinv<<<NB * WC, 256, 0, stream>>>(Op, t1, S, WC, 2, 0, 0);
        k_blockup<<<2048, 256, 0, stream>>>(xc, t1, ww[L], wb[L]);
    }

    k_fc<<<2048, 256, 0, stream>>>(xc, fc1w, fc1b, fc2w, fc2b, out);
}

// Round 14
// 4061.934 us; speedup vs baseline: 1.6659x; 1.6659x over previous
//
#include <hip/hip_runtime.h>
#include <math.h>

#define NB 16      // batch
#define NN 128     // spatial
#define WC 64      // width / channels
#define DD 64      // D1=D2
#define NP 66      // D + BW - 1

typedef float v4f __attribute__((ext_vector_type(4)));
typedef unsigned int u32;

__device__ __forceinline__ float gelu_f(float x) {
    return 0.5f * x * (1.0f + erff(x * 0.70710678118654752f));
}

// width-16 global->LDS direct copy (dest = wave-uniform base + lane*16)
__device__ __forceinline__ void gload16(const float* g, float* l) {
    __builtin_amdgcn_global_load_lds(
        (const __attribute__((address_space(1))) u32*)g,
        (__attribute__((address_space(3))) u32*)l, 16, 0, 0);
}

// ---------------- DST matrix ----------------
__global__ void k_dst(float* __restrict__ S) {
    int idx = blockIdx.x * 256 + threadIdx.x;   // 16384
    int k = idx >> 7, j = idx & 127;
    double arg = 3.14159265358979323846 * (double)((k + 1) * (j + 1)) / 129.0;
    S[idx] = (float)(sqrt(2.0 / 129.0) * sin(arg));
}

// ---------------- transpose input (B,N,N,3) -> (B,64ch,N,N) ch0..2 ----------------
__global__ void k_tin(const float* __restrict__ in, float* __restrict__ xc) {
    int idx = blockIdx.x * 256 + threadIdx.x;   // 16*3*16384
    int j = idx & 127;
    int i = (idx >> 7) & 127;
    int t = idx >> 14;           // b*3 + c
    int b = t / 3, c = t - b * 3;
    xc[(((size_t)b * WC + c) << 14) + i * 128 + j] =
        in[((size_t)(b * 128 + i) * 128 + j) * 3 + c];
}

// ---------------- forward transform, compact 66x(68-padded) output ----------------
// (round-2 compute; output rows padded to 68 floats, channel stride 4488, so
//  mix6's width-16 global_load_lds sources are all 16B-aligned and LDS-linear)
__global__ __launch_bounds__(256) void k_tfwd66(const float* __restrict__ Xg,
                                                float* __restrict__ Yc,
                                                const float* __restrict__ Sg,
                                                int Cact) {
    __shared__ float sSt[80 * 132];
    __shared__ float sU[66 * 132];
    int bid = blockIdx.x;
    int b = bid / Cact, c = bid - b * Cact;
    const float* X = Xg + (((size_t)b * WC + c) << 14);
    int tid = threadIdx.x;
    int tx = tid & 15, ty = tid >> 4;
    for (int l = tid; l < 80 * 128; l += 256)
        sSt[(l >> 7) * 132 + (l & 127)] = Sg[l];
    float acc[8][5];
#pragma unroll
    for (int r = 0; r < 8; ++r)
#pragma unroll
        for (int q = 0; q < 5; ++q) acc[r][q] = 0.f;
    for (int jh = 0; jh < 2; ++jh) {
        __syncthreads();
        for (int l = tid; l < 8192; l += 256)
            sU[(l >> 6) * 68 + (l & 63)] = X[((l >> 6) << 7) + jh * 64 + (l & 63)];
        __syncthreads();
        for (int jj = 0; jj < 64; jj += 4) {
            float4 xv[8], sv[5];
#pragma unroll
            for (int r = 0; r < 8; ++r)
                xv[r] = *(const float4*)&sU[(ty + 16 * r) * 68 + jj];
#pragma unroll
            for (int q = 0; q < 5; ++q)
                sv[q] = *(const float4*)&sSt[(tx + 16 * q) * 132 + jh * 64 + jj];
#pragma unroll
            for (int r = 0; r < 8; ++r)
#pragma unroll
                for (int q = 0; q < 5; ++q) {
                    acc[r][q] += xv[r].x * sv[q].x;
                    acc[r][q] += xv[r].y * sv[q].y;
                    acc[r][q] += xv[r].z * sv[q].z;
                    acc[r][q] += xv[r].w * sv[q].w;
                }
        }
    }
    __syncthreads();
#pragma unroll
    for (int q = 0; q < 5; ++q) {
        int k = tx + 16 * q;
        if (k < 66) {
#pragma unroll
            for (int r = 0; r < 8; ++r)
                sU[k * 132 + ty + 16 * r] = acc[r][q];
        }
    }
    __syncthreads();
    float a2[5][5];
#pragma unroll
    for (int r = 0; r < 5; ++r)
#pragma unroll
        for (int q = 0; q < 5; ++q) a2[r][q] = 0.f;
    for (int i0 = 0; i0 < 128; i0 += 4) {
        float4 sv[5], tv[5];
#pragma unroll
        for (int r = 0; r < 5; ++r)
            sv[r] = *(const float4*)&sSt[(ty + 16 * r) * 132 + i0];
#pragma unroll
        for (int q = 0; q < 5; ++q) {
            int m = tx + 16 * q;
            if (m < 66) tv[q] = *(const float4*)&sU[m * 132 + i0];
            else { tv[q].x = 0.f; tv[q].y = 0.f; tv[q].z = 0.f; tv[q].w = 0.f; }
        }
#pragma unroll
        for (int r = 0; r < 5; ++r)
#pragma unroll
            for (int q = 0; q < 5; ++q) {
                a2[r][q] += sv[r].x * tv[q].x;
                a2[r][q] += sv[r].y * tv[q].y;
                a2[r][q] += sv[r].z * tv[q].z;
                a2[r][q] += sv[r].w * tv[q].w;
            }
    }
    float* Y = Yc + (size_t)(b * WC + c) * 4488;    // 66 rows x 68-stride
#pragma unroll
    for (int r = 0; r < 5; ++r) {
        int kk = ty + 16 * r;
        if (kk < 66) {
#pragma unroll
            for (int q = 0; q < 5; ++q) {
                int m = tx + 16 * q;
                if (m < 66) Y[kk * 68 + m] = a2[r][q];
            }
        }
    }
}

// ---------------- inverse transform + partial-sum + optional gelu/ch-offset ----------
// v5: DST parity fold on OUTPUT cols (stage 1) and OUTPUT rows (stage 2).
// FMA 6144->3072, LDS reads 704->512, sS 16KB -> 3 blocks/CU. (round-10 win)
__global__ __launch_bounds__(256, 3) void k_tinv(const float* __restrict__ Op,
                                                 float* __restrict__ Yg,
                                                 const float* __restrict__ Sg,
                                                 int Cact, int ncc, int ch_off, int do_gelu) {
    __shared__ float sS[64 * 64];      // S rows 0..63, cols 0..63 (16 KB)
    __shared__ float sXT[64 * 132];    // union: X (stride 66) then T (stride 132)
    int bid = blockIdx.x;
    int b = bid / Cact, c = bid - b * Cact;
    const float* X = Op + ((size_t)(b * WC + c) << 12);
    const size_t cstride = (size_t)NB * WC * 4096;
    float* Y = Yg + (((size_t)b * WC + c + ch_off) << 14);
    int tid = threadIdx.x;
    for (int l = tid; l < 4096; l += 256)
        sS[l] = Sg[((l >> 6) << 7) + (l & 63)];
    for (int l = tid; l < 4096; l += 256) {
        int r = l >> 6, q = l & 63;
        float v = X[l];
        for (int cc = 1; cc < ncc; ++cc) v += X[cc * cstride + l];
        sXT[r * 66 + q] = v;            // stride 66: b64-aligned pair reads later
    }
    __syncthreads();
    int cg = tid & 7;
    int rg = tid >> 3;                  // 0..31
    // ---- stage 1 (col-fold): P/M over even/odd j, cols c = cg*4+32m' (m'<2) ----
    v4f aP[2][2], aM[2][2];
#pragma unroll
    for (int r = 0; r < 2; ++r)
#pragma unroll
        for (int m = 0; m < 2; ++m) {
            aP[r][m].x = 0.f; aP[r][m].y = 0.f; aP[r][m].z = 0.f; aP[r][m].w = 0.f;
            aM[r][m].x = 0.f; aM[r][m].y = 0.f; aM[r][m].z = 0.f; aM[r][m].w = 0.f;
        }
    for (int jp = 0; jp < 32; ++jp) {
        float2 x0 = *(const float2*)&sXT[(rg * 2 + 0) * 66 + 2 * jp];
        float2 x1 = *(const float2*)&sXT[(rg * 2 + 1) * 66 + 2 * jp];
#pragma unroll
        for (int m = 0; m < 2; ++m) {
            v4f se = *(const v4f*)&sS[(2 * jp) * 64 + cg * 4 + 32 * m];
            v4f so = *(const v4f*)&sS[(2 * jp + 1) * 64 + cg * 4 + 32 * m];
            aP[0][m] += se * x0.x;  aM[0][m] += so * x0.y;
            aP[1][m] += se * x1.x;  aM[1][m] += so * x1.y;
        }
    }
    __syncthreads();                    // all X reads done; reuse buffer for T
#pragma unroll
    for (int r = 0; r < 2; ++r)
#pragma unroll
        for (int m = 0; m < 2; ++m) {
            v4f tlo = aP[r][m] + aM[r][m];
            v4f td  = aP[r][m] - aM[r][m];
            v4f thi; thi.x = td.w; thi.y = td.z; thi.z = td.y; thi.w = td.x;
            int row = rg * 2 + r;
            *(v4f*)&sXT[row * 132 + cg * 4 + 32 * m] = tlo;
            *(v4f*)&sXT[row * 132 + 124 - cg * 4 - 32 * m] = thi;
        }
    __syncthreads();
    // ---- stage 2 (row-fold): P/M over even/odd i; rows rg*2+r and 127-(rg*2+r) ----
    v4f p2[2][4], m2[2][4];
#pragma unroll
    for (int r = 0; r < 2; ++r)
#pragma unroll
        for (int m = 0; m < 4; ++m) {
            p2[r][m].x = 0.f; p2[r][m].y = 0.f; p2[r][m].z = 0.f; p2[r][m].w = 0.f;
            m2[r][m].x = 0.f; m2[r][m].y = 0.f; m2[r][m].z = 0.f; m2[r][m].w = 0.f;
        }
    for (int ip = 0; ip < 32; ++ip) {
        float2 sve = *(const float2*)&sS[(2 * ip) * 64 + rg * 2];
        float2 svo = *(const float2*)&sS[(2 * ip + 1) * 64 + rg * 2];
#pragma unroll
        for (int m = 0; m < 4; ++m) {
            v4f te = *(const v4f*)&sXT[(2 * ip) * 132 + cg * 4 + 32 * m];
            v4f to = *(const v4f*)&sXT[(2 * ip + 1) * 132 + cg * 4 + 32 * m];
            p2[0][m] += te * sve.x;  p2[1][m] += te * sve.y;
            m2[0][m] += to * svo.x;  m2[1][m] += to * svo.y;
        }
    }
#pragma unroll
    for (int r = 0; r < 2; ++r) {
        int rlo = rg * 2 + r, rhi = 127 - rlo;
#pragma unroll
        for (int m = 0; m < 4; ++m) {
            v4f ylo = p2[r][m] + m2[r][m];
            v4f yhi = p2[r][m] - m2[r][m];
            if (do_gelu) {
                ylo.x = gelu_f(ylo.x); ylo.y = gelu_f(ylo.y);
                ylo.z = gelu_f(ylo.z); ylo.w = gelu_f(ylo.w);
                yhi.x = gelu_f(yhi.x); yhi.y = gelu_f(yhi.y);
                yhi.z = gelu_f(yhi.z); yhi.w = gelu_f(yhi.w);
            }
            *(v4f*)&Y[rlo * 128 + cg * 4 + 32 * m] = ylo;
            *(v4f*)&Y[rhi * 128 + cg * 4 + 32 * m] = yhi;
        }
    }
}

// ---------------- spectral channel mixing v8 ----------------
// 2 ocs/thread (halves A-LDS work + A-restage traffic) with weight state cut
// to per-pi 3-deep ping-pong: wA[2][3]+wB[2][3] = 48 VGPR (was 288 in the
// round-13 spill). Live budget: acc 128 + wv 48 + addr/temps ~35 = ~210,
// under the CALIBRATED 256 arch-VGPR/wave cap (round-13: launch_bounds(256,1)
// caps at 256, not 512). No sched_barrier pins (round-11 lesson) — compiler
// sinks loads freely. Each pi's 3-load group issued one FMA block ahead.
// ccb=4 (cper=16) -> grid 512 = 2 blocks/CU. FMA nesting per output
// unchanged; c-grouping 2->4 shifts absmax slightly (reassoc only).
// [Tripwire: VGPR_Count ~210-240 and ~0.8 GB/dispatch expected; 256 + GBs
//  of WRITE_SIZE = spill -> revert to round-12, mix6 closed.]
__global__ __launch_bounds__(256, 1) void k_mix6(const float* __restrict__ Ac,
                                                 const float* __restrict__ Wt,
                                                 float* __restrict__ Op,
                                                 int Cin, int Cout, int cper) {
    __shared__ __align__(16) float sa[2][16 * 4 * 68];   // 2 x 4352 floats
    int bx = blockIdx.x;         // 0..31 (x pair)
    int ocb = blockIdx.y;        // 0..3
    int ccb = blockIdx.z;
    int c0 = ccb * cper;
    int c1 = c0 + cper; if (c1 > Cin) c1 = Cin;
    int tid = threadIdx.x;
    int yq = tid & 15, ocl = (tid >> 4) & 7, xh = tid >> 7;
    int x = bx * 2 + xh;
    int oc0 = ocb * 16 + ocl;
    int oc1 = oc0 + 8;
    bool ok0 = oc0 < Cout, ok1 = oc1 < Cout;
    v4f z4; z4.x = 0.f; z4.y = 0.f; z4.z = 0.f; z4.w = 0.f;

    const size_t wstep = (size_t)Cout * 4096;
    const float* wb0 = Wt + (size_t)(ok0 ? oc0 : 0) * 4096 + x * 64 + (yq << 2);
    const float* wb1 = Wt + (size_t)(ok1 ? oc1 : 0) * 4096 + x * 64 + (yq << 2);

    // gload16 slots: LDS v4f v = tid + 256k, float f = 4v; window [bb][4][68]
    // maps to global channel offset bx*136 + (f % 272) within batch bb = f/272.
    int gbase[5];
#pragma unroll
    for (int k = 0; k < 5; ++k) {
        int f = 4 * tid + 1024 * k;
        int fv = (f < 4352) ? f : 0;
        int bb = fv / 272; int off = fv - bb * 272;
        gbase[k] = bb * (WC * 4488) + bx * 136 + off;
    }

    float acc[2][16][4];
#pragma unroll
    for (int o2 = 0; o2 < 2; ++o2)
#pragma unroll
        for (int bb = 0; bb < 16; ++bb)
#pragma unroll
            for (int k = 0; k < 4; ++k) acc[o2][bb][k] = 0.f;

    v4f wA[2][3], wB[2][3];

    auto stageA = [&](int cc, float* dst) {
        const float* src = Ac + (size_t)cc * 4488;
#pragma unroll
        for (int k = 0; k < 4; ++k)
            gload16(src + gbase[k], dst + 4 * tid + 1024 * k);
        if (tid < 64) gload16(src + gbase[4], dst + 4 * tid + 4096);
    };
    auto loadW3 = [&](int cc, int pi, v4f (&wv)[2][3]) {
#pragma unroll
        for (int pj = 0; pj < 3; ++pj) {
            size_t off = ((size_t)cc * 9 + pi * 3 + pj) * wstep;
            wv[0][pj] = ok0 ? __builtin_nontemporal_load((const v4f*)(wb0 + off)) : z4;
            wv[1][pj] = ok1 ? __builtin_nontemporal_load((const v4f*)(wb1 + off)) : z4;
        }
    };
    auto fmaPi = [&](const float* sab, int pi, const v4f (&wv)[2][3]) {
#pragma unroll
        for (int bb = 0; bb < 16; ++bb) {
            const float* sp = &sab[(bb * 4 + xh + pi) * 68 + (yq << 2)];
            float4 s0 = *(const float4*)sp;
            float2 s1 = *(const float2*)(sp + 4);
            float sv[6] = {s0.x, s0.y, s0.z, s0.w, s1.x, s1.y};
#pragma unroll
            for (int k = 0; k < 4; ++k)
#pragma unroll
                for (int pj = 0; pj < 3; ++pj) {
                    acc[0][bb][k] = fmaf(sv[k + pj], wv[0][pj][k], acc[0][bb][k]);
                    acc[1][bb][k] = fmaf(sv[k + pj], wv[1][pj][k], acc[1][bb][k]);
                }
        }
    };

    // ---- prologue: stage A[c0]; weights (c0, pi0) ----
    stageA(c0, sa[0]);
    loadW3(c0, 0, wA);
    __syncthreads();

    int cur = 0;
    int c = c0;
    for (;;) {
        {   // A-iter: wA holds (c, pi0)
            bool hn = (c + 1) < c1;
            if (hn) stageA(c + 1, sa[cur ^ 1]);
            loadW3(c, 1, wB);
            fmaPi(sa[cur], 0, wA);
            loadW3(c, 2, wA);
            fmaPi(sa[cur], 1, wB);
            if (hn) loadW3(c + 1, 0, wB);
            fmaPi(sa[cur], 2, wA);
            if (hn) { __syncthreads(); cur ^= 1; }
        }
        if (++c >= c1) break;
        {   // B-iter: wB holds (c, pi0)
            bool hn = (c + 1) < c1;
            if (hn) stageA(c + 1, sa[cur ^ 1]);
            loadW3(c, 1, wA);
            fmaPi(sa[cur], 0, wB);
            loadW3(c, 2, wB);
            fmaPi(sa[cur], 1, wA);
            if (hn) loadW3(c + 1, 0, wA);
            fmaPi(sa[cur], 2, wB);
            if (hn) { __syncthreads(); cur ^= 1; }
        }
        if (++c >= c1) break;
    }

    float* Opc = Op + (size_t)ccb * ((size_t)NB * WC * 4096);
#pragma unroll
    for (int o2 = 0; o2 < 2; ++o2) {
        bool ok = o2 ? ok1 : ok0;
        int oc = o2 ? oc1 : oc0;
        if (ok) {
#pragma unroll
            for (int bb = 0; bb < 16; ++bb) {
                float4 o4;
                o4.x = acc[o2][bb][0]; o4.y = acc[o2][bb][1];
                o4.z = acc[o2][bb][2]; o4.w = acc[o2][bb][3];
                *(float4*)&Opc[(((size_t)bb * WC + oc) << 12) + x * 64 + (yq << 2)] = o4;
            }
        }
    }
}

// ---------------- block update: xc = xc + gelu(conv1x1(xc)+bias + t1) ----------------
// v2: x-row hoisted to 64 VGPRs, LDS-staged weights read as broadcast b128
// (measured faster than wave-uniform global loads — round 4).
__global__ __launch_bounds__(256) void k_blockup(float* __restrict__ xc,
                                                 const float* __restrict__ sp,
                                                 const float* __restrict__ wmat,
                                                 const float* __restrict__ bias) {
    __shared__ float sw[64 * 64];
    __shared__ float sx[128 * 65];
    __shared__ float sb[64];
    int bi = blockIdx.x;          // b*128 + i
    int b = bi >> 7, i = bi & 127;
    int tid = threadIdx.x;
    for (int l = tid; l < 4096; l += 256) sw[l] = wmat[l];
    if (tid < 64) sb[tid] = bias[tid];
    for (int l = tid; l < 8192; l += 256) {
        int c = l >> 7, j = l & 127;
        sx[j * 65 + c] = xc[(((size_t)b * WC + c) << 14) + i * 128 + j];
    }
    __syncthreads();
    int j = tid & 127, h = tid >> 7;
    float xr[64];
#pragma unroll
    for (int c = 0; c < 64; ++c) xr[c] = sx[j * 65 + c];
#pragma unroll 2
    for (int o = 0; o < 32; ++o) {
        int oc = h * 32 + o;
        float a = sb[oc];
#pragma unroll
        for (int c4 = 0; c4 < 16; ++c4) {
            v4f w4 = *(const v4f*)&sw[oc * 64 + c4 * 4];
            a = fmaf(xr[c4 * 4 + 0], w4.x, a);
            a = fmaf(xr[c4 * 4 + 1], w4.y, a);
            a = fmaf(xr[c4 * 4 + 2], w4.z, a);
            a = fmaf(xr[c4 * 4 + 3], w4.w, a);
        }
        size_t gi = (((size_t)b * WC + oc) << 14) + i * 128 + j;
        float v = a + sp[gi];
        xc[gi] = sx[j * 65 + oc] + gelu_f(v);
    }
}

// ---------------- final MLP: out = (gelu(x@W1+b1))@W2 + b2 ----------------
// v2: x-row in registers, W1 staged transposed so the inner read is broadcast b128.
__global__ __launch_bounds__(256) void k_fc(const float* __restrict__ xc,
                                            const float* __restrict__ W1,
                                            const float* __restrict__ b1,
                                            const float* __restrict__ W2,
                                            const float* __restrict__ b2,
                                            float* __restrict__ out) {
    __shared__ float sW1T[128 * 68];   // [oo][c], 16B-aligned rows
    __shared__ float sx[128 * 65];
    __shared__ float sW2[128];
    __shared__ float sb1[128];
    __shared__ float spart[256];
    int bi = blockIdx.x; int b = bi >> 7, i = bi & 127;
    int tid = threadIdx.x;
    for (int l = tid; l < 8192; l += 256) {
        int c = l >> 7, oo = l & 127;
        sW1T[oo * 68 + c] = W1[l];
    }
    if (tid < 128) { sW2[tid] = W2[tid]; sb1[tid] = b1[tid]; }
    for (int l = tid; l < 8192; l += 256) {
        int c = l >> 7, j = l & 127;
        sx[j * 65 + c] = xc[(((size_t)b * WC + c) << 14) + i * 128 + j];
    }
    __syncthreads();
    int j = tid & 127, h = tid >> 7;
    float xr[64];
#pragma unroll
    for (int c = 0; c < 64; ++c) xr[c] = sx[j * 65 + c];
    float part = 0.f;
#pragma unroll 2
    for (int o = 0; o < 64; ++o) {
        int oo = h * 64 + o;
        float a = sb1[oo];
#pragma unroll
        for (int c4 = 0; c4 < 16; ++c4) {
            v4f w4 = *(const v4f*)&sW1T[oo * 68 + c4 * 4];
            a = fmaf(xr[c4 * 4 + 0], w4.x, a);
            a = fmaf(xr[c4 * 4 + 1], w4.y, a);
            a = fmaf(xr[c4 * 4 + 2], w4.z, a);
            a = fmaf(xr[c4 * 4 + 3], w4.w, a);
        }
        part += gelu_f(a) * sW2[oo];
    }
    spart[j * 2 + h] = part;
    __syncthreads();
    if (h == 0) out[(size_t)bi * 128 + j] = spart[j * 2] + spart[j * 2 + 1] + b2[0];
}

extern "C" void kernel_launch(void* const* d_in, const int* in_sizes, int n_in,
                              void* d_out, int out_size, void* d_ws, size_t ws_size,
                              hipStream_t stream) {
    (void)in_sizes; (void)n_in; (void)out_size; (void)ws_size;
    const float* x_in    = (const float*)d_in[0];
    const float* convl_w = (const float*)d_in[1];
    const float* conv_w[4] = {(const float*)d_in[2], (const float*)d_in[3],
                              (const float*)d_in[4], (const float*)d_in[5]};
    const float* ww[4] = {(const float*)d_in[6], (const float*)d_in[8],
                          (const float*)d_in[10], (const float*)d_in[12]};
    const float* wb[4] = {(const float*)d_in[7], (const float*)d_in[9],
                          (const float*)d_in[11], (const float*)d_in[13]};
    const float* fc1w = (const float*)d_in[14];
    const float* fc1b = (const float*)d_in[15];
    const float* fc2w = (const float*)d_in[16];
    const float* fc2b = (const float*)d_in[17];
    float* out = (float*)d_out;

    float* S   = (float*)d_ws;                       // 16384
    float* xc  = S + 16384;                          // 16.8M floats
    float* t1  = xc + (size_t)NB * WC * 16384;       // 16.8M floats
    float* tA  = t1 + (size_t)NB * WC * 16384;       // 4.60M floats (66x68-padded)
    float* Op  = tA + (size_t)NB * WC * 4488;        // 4 x 4.19M partials

    k_dst<<<64, 256, 0, stream>>>(S);
    k_tin<<<3072, 256, 0, stream>>>(x_in, xc);

    // lifting: u3 -> wswano(3 -> 61) -> gelu -> channels 3..63
    k_tfwd66<<<NB * 3, 256, 0, stream>>>(xc, tA, S, 3);
    k_mix6<<<dim3(32, 4, 1), 256, 0, stream>>>(tA, convl_w, Op, 3, 61, 3);
    k_tinv<<<NB * 61, 256, 0, stream>>>(Op, xc, S, 61, 1, 3, 1);

    for (int L = 0; L < 4; ++L) {
        k_tfwd66<<<NB * WC, 256, 0, stream>>>(xc, tA, S, WC);
        k_mix6<<<dim3(32, 4, 4), 256, 0, stream>>>(tA, conv_w[L], Op, WC, WC, 16);
        k_tinv<<<NB * WC, 256, 0, stream>>>(Op, t1, S, WC, 4, 0, 0);
        k_blockup<<<2048, 256, 0, stream>>>(xc, t1, ww[L], wb[L]);
    }

    k_fc<<<2048, 256, 0, stream>>>(xc, fc1w, fc1b, fc2w, fc2b, out);
}

// Round 15
// 1607.029 us; speedup vs baseline: 4.2108x; 2.5276x over previous
//
#include <hip/hip_runtime.h>
#include <math.h>

#define NB 16      // batch
#define NN 128     // spatial
#define WC 64      // width / channels
#define DD 64      // D1=D2
#define NP 66      // D + BW - 1

typedef float v4f __attribute__((ext_vector_type(4)));
typedef unsigned int u32;

__device__ __forceinline__ float gelu_f(float x) {
    return 0.5f * x * (1.0f + erff(x * 0.70710678118654752f));
}

// width-16 global->LDS direct copy (dest = wave-uniform base + lane*16)
__device__ __forceinline__ void gload16(const float* g, float* l) {
    __builtin_amdgcn_global_load_lds(
        (const __attribute__((address_space(1))) u32*)g,
        (__attribute__((address_space(3))) u32*)l, 16, 0, 0);
}

// ---------------- DST matrix ----------------
__global__ void k_dst(float* __restrict__ S) {
    int idx = blockIdx.x * 256 + threadIdx.x;   // 16384
    int k = idx >> 7, j = idx & 127;
    double arg = 3.14159265358979323846 * (double)((k + 1) * (j + 1)) / 129.0;
    S[idx] = (float)(sqrt(2.0 / 129.0) * sin(arg));
}

// ---------------- transpose input (B,N,N,3) -> (B,64ch,N,N) ch0..2 ----------------
__global__ void k_tin(const float* __restrict__ in, float* __restrict__ xc) {
    int idx = blockIdx.x * 256 + threadIdx.x;   // 16*3*16384
    int j = idx & 127;
    int i = (idx >> 7) & 127;
    int t = idx >> 14;           // b*3 + c
    int b = t / 3, c = t - b * 3;
    xc[(((size_t)b * WC + c) << 14) + i * 128 + j] =
        in[((size_t)(b * 128 + i) * 128 + j) * 3 + c];
}

// ---------------- forward transform, compact 66x(68-padded) output ----------------
// (round-2 compute; output rows padded to 68 floats, channel stride 4488, so
//  mix6's width-16 global_load_lds sources are all 16B-aligned and LDS-linear)
__global__ __launch_bounds__(256) void k_tfwd66(const float* __restrict__ Xg,
                                                float* __restrict__ Yc,
                                                const float* __restrict__ Sg,
                                                int Cact) {
    __shared__ float sSt[80 * 132];
    __shared__ float sU[66 * 132];
    int bid = blockIdx.x;
    int b = bid / Cact, c = bid - b * Cact;
    const float* X = Xg + (((size_t)b * WC + c) << 14);
    int tid = threadIdx.x;
    int tx = tid & 15, ty = tid >> 4;
    for (int l = tid; l < 80 * 128; l += 256)
        sSt[(l >> 7) * 132 + (l & 127)] = Sg[l];
    float acc[8][5];
#pragma unroll
    for (int r = 0; r < 8; ++r)
#pragma unroll
        for (int q = 0; q < 5; ++q) acc[r][q] = 0.f;
    for (int jh = 0; jh < 2; ++jh) {
        __syncthreads();
        for (int l = tid; l < 8192; l += 256)
            sU[(l >> 6) * 68 + (l & 63)] = X[((l >> 6) << 7) + jh * 64 + (l & 63)];
        __syncthreads();
        for (int jj = 0; jj < 64; jj += 4) {
            float4 xv[8], sv[5];
#pragma unroll
            for (int r = 0; r < 8; ++r)
                xv[r] = *(const float4*)&sU[(ty + 16 * r) * 68 + jj];
#pragma unroll
            for (int q = 0; q < 5; ++q)
                sv[q] = *(const float4*)&sSt[(tx + 16 * q) * 132 + jh * 64 + jj];
#pragma unroll
            for (int r = 0; r < 8; ++r)
#pragma unroll
                for (int q = 0; q < 5; ++q) {
                    acc[r][q] += xv[r].x * sv[q].x;
                    acc[r][q] += xv[r].y * sv[q].y;
                    acc[r][q] += xv[r].z * sv[q].z;
                    acc[r][q] += xv[r].w * sv[q].w;
                }
        }
    }
    __syncthreads();
#pragma unroll
    for (int q = 0; q < 5; ++q) {
        int k = tx + 16 * q;
        if (k < 66) {
#pragma unroll
            for (int r = 0; r < 8; ++r)
                sU[k * 132 + ty + 16 * r] = acc[r][q];
        }
    }
    __syncthreads();
    float a2[5][5];
#pragma unroll
    for (int r = 0; r < 5; ++r)
#pragma unroll
        for (int q = 0; q < 5; ++q) a2[r][q] = 0.f;
    for (int i0 = 0; i0 < 128; i0 += 4) {
        float4 sv[5], tv[5];
#pragma unroll
        for (int r = 0; r < 5; ++r)
            sv[r] = *(const float4*)&sSt[(ty + 16 * r) * 132 + i0];
#pragma unroll
        for (int q = 0; q < 5; ++q) {
            int m = tx + 16 * q;
            if (m < 66) tv[q] = *(const float4*)&sU[m * 132 + i0];
            else { tv[q].x = 0.f; tv[q].y = 0.f; tv[q].z = 0.f; tv[q].w = 0.f; }
        }
#pragma unroll
        for (int r = 0; r < 5; ++r)
#pragma unroll
            for (int q = 0; q < 5; ++q) {
                a2[r][q] += sv[r].x * tv[q].x;
                a2[r][q] += sv[r].y * tv[q].y;
                a2[r][q] += sv[r].z * tv[q].z;
                a2[r][q] += sv[r].w * tv[q].w;
            }
    }
    float* Y = Yc + (size_t)(b * WC + c) * 4488;    // 66 rows x 68-stride
#pragma unroll
    for (int r = 0; r < 5; ++r) {
        int kk = ty + 16 * r;
        if (kk < 66) {
#pragma unroll
            for (int q = 0; q < 5; ++q) {
                int m = tx + 16 * q;
                if (m < 66) Y[kk * 68 + m] = a2[r][q];
            }
        }
    }
}

// ---------------- inverse transform + partial-sum + optional gelu/ch-offset ----------
// v5: DST parity fold on OUTPUT cols (stage 1) and OUTPUT rows (stage 2):
//   S[k][127-j] = (-1)^k S[k][j]  =>
//   T[i][c]    = P+M, T[i][127-c]   = P-M  (P/M = even/odd-j partial sums, c<64)
//   Y[row][*]  = P+M, Y[127-row][*] = P-M  (P/M = even/odd-i partial sums, row<64)
// FMA 6144->3072, LDS reads 704->512. Folded stages need only S[:64][:64]
// -> sS shrinks 32KB->16KB -> LDS 49.8KB -> 3 blocks/CU (was 2).
// Barrier skeleton unchanged: stage -> bar -> s1(read) -> bar -> T-write -> bar -> s2.
__global__ __launch_bounds__(256, 3) void k_tinv(const float* __restrict__ Op,
                                                 float* __restrict__ Yg,
                                                 const float* __restrict__ Sg,
                                                 int Cact, int ncc, int ch_off, int do_gelu) {
    __shared__ float sS[64 * 64];      // S rows 0..63, cols 0..63 (16 KB)
    __shared__ float sXT[64 * 132];    // union: X (stride 66) then T (stride 132)
    int bid = blockIdx.x;
    int b = bid / Cact, c = bid - b * Cact;
    const float* X = Op + ((size_t)(b * WC + c) << 12);
    const size_t cstride = (size_t)NB * WC * 4096;
    float* Y = Yg + (((size_t)b * WC + c + ch_off) << 14);
    int tid = threadIdx.x;
    for (int l = tid; l < 4096; l += 256)
        sS[l] = Sg[((l >> 6) << 7) + (l & 63)];
    for (int l = tid; l < 4096; l += 256) {
        int r = l >> 6, q = l & 63;
        float v = X[l];
        for (int cc = 1; cc < ncc; ++cc) v += X[cc * cstride + l];
        sXT[r * 66 + q] = v;            // stride 66: b64-aligned pair reads later
    }
    __syncthreads();
    int cg = tid & 7;
    int rg = tid >> 3;                  // 0..31
    // ---- stage 1 (col-fold): P/M over even/odd j, cols c = cg*4+32m' (m'<2) ----
    v4f aP[2][2], aM[2][2];
#pragma unroll
    for (int r = 0; r < 2; ++r)
#pragma unroll
        for (int m = 0; m < 2; ++m) {
            aP[r][m].x = 0.f; aP[r][m].y = 0.f; aP[r][m].z = 0.f; aP[r][m].w = 0.f;
            aM[r][m].x = 0.f; aM[r][m].y = 0.f; aM[r][m].z = 0.f; aM[r][m].w = 0.f;
        }
    for (int jp = 0; jp < 32; ++jp) {
        float2 x0 = *(const float2*)&sXT[(rg * 2 + 0) * 66 + 2 * jp];
        float2 x1 = *(const float2*)&sXT[(rg * 2 + 1) * 66 + 2 * jp];
#pragma unroll
        for (int m = 0; m < 2; ++m) {
            v4f se = *(const v4f*)&sS[(2 * jp) * 64 + cg * 4 + 32 * m];
            v4f so = *(const v4f*)&sS[(2 * jp + 1) * 64 + cg * 4 + 32 * m];
            aP[0][m] += se * x0.x;  aM[0][m] += so * x0.y;
            aP[1][m] += se * x1.x;  aM[1][m] += so * x1.y;
        }
    }
    __syncthreads();                    // all X reads done; reuse buffer for T
#pragma unroll
    for (int r = 0; r < 2; ++r)
#pragma unroll
        for (int m = 0; m < 2; ++m) {
            v4f tlo = aP[r][m] + aM[r][m];
            v4f td  = aP[r][m] - aM[r][m];
            v4f thi; thi.x = td.w; thi.y = td.z; thi.z = td.y; thi.w = td.x;
            int row = rg * 2 + r;
            *(v4f*)&sXT[row * 132 + cg * 4 + 32 * m] = tlo;
            *(v4f*)&sXT[row * 132 + 124 - cg * 4 - 32 * m] = thi;
        }
    __syncthreads();
    // ---- stage 2 (row-fold): P/M over even/odd i; rows rg*2+r and 127-(rg*2+r) ----
    v4f p2[2][4], m2[2][4];
#pragma unroll
    for (int r = 0; r < 2; ++r)
#pragma unroll
        for (int m = 0; m < 4; ++m) {
            p2[r][m].x = 0.f; p2[r][m].y = 0.f; p2[r][m].z = 0.f; p2[r][m].w = 0.f;
            m2[r][m].x = 0.f; m2[r][m].y = 0.f; m2[r][m].z = 0.f; m2[r][m].w = 0.f;
        }
    for (int ip = 0; ip < 32; ++ip) {
        float2 sve = *(const float2*)&sS[(2 * ip) * 64 + rg * 2];
        float2 svo = *(const float2*)&sS[(2 * ip + 1) * 64 + rg * 2];
#pragma unroll
        for (int m = 0; m < 4; ++m) {
            v4f te = *(const v4f*)&sXT[(2 * ip) * 132 + cg * 4 + 32 * m];
            v4f to = *(const v4f*)&sXT[(2 * ip + 1) * 132 + cg * 4 + 32 * m];
            p2[0][m] += te * sve.x;  p2[1][m] += te * sve.y;
            m2[0][m] += to * svo.x;  m2[1][m] += to * svo.y;
        }
    }
#pragma unroll
    for (int r = 0; r < 2; ++r) {
        int rlo = rg * 2 + r, rhi = 127 - rlo;
#pragma unroll
        for (int m = 0; m < 4; ++m) {
            v4f ylo = p2[r][m] + m2[r][m];
            v4f yhi = p2[r][m] - m2[r][m];
            if (do_gelu) {
                ylo.x = gelu_f(ylo.x); ylo.y = gelu_f(ylo.y);
                ylo.z = gelu_f(ylo.z); ylo.w = gelu_f(ylo.w);
                yhi.x = gelu_f(yhi.x); yhi.y = gelu_f(yhi.y);
                yhi.z = gelu_f(yhi.z); yhi.w = gelu_f(yhi.w);
            }
            *(v4f*)&Y[rlo * 128 + cg * 4 + 32 * m] = ylo;
            *(v4f*)&Y[rhi * 128 + cg * 4 + 32 * m] = yhi;
        }
    }
}

// ---------------- spectral channel mixing v4 (FINAL — round-7 known-good) ----------------
// Thread map: (ocl 0..7, yq 0..15, xh 0..1); block covers 2 x-rows; thread owns
// all 16 batches -> every thread's 9 weight loads are UNIQUE. A staged via
// width-16 global_load_lds ([bb][4][68] windows, tA rows 68-padded).
// 1-deep weight prefetch, 1 barrier/c. ~180 VGPR, 2 blocks/CU.
// [CLOSED after 4 spill failures (r8/r11/r13/r14): any 2-oc widening
//  (acc 128) or weight-lifetime pinning overflows the 256-VGPR/wave arch cap
//  (calibrated r13: launch_bounds(256,1) allocates 256 max, not 512) and
//  spills to scratch (0.9-10 GB/dispatch). acc[16][4] + 9-wide transient
//  weight dbuf + addressing is the practical budget; the compiler's freedom
//  to sink prefetch loads is what keeps v4 spill-free. Residual ~1.9x gap
//  over the 96 us/layer weight floor is paid for by register-file physics.]
__global__ __launch_bounds__(256, 2) void k_mix6(const float* __restrict__ Ac,
                                                 const float* __restrict__ Wt,
                                                 float* __restrict__ Op,
                                                 int Cin, int Cout, int cper) {
    __shared__ __align__(16) float sa[2][16 * 4 * 68];   // 2 x 4352 floats
    int bx = blockIdx.x;         // 0..31 (x pair)
    int ocb = blockIdx.y;        // 0..7
    int ccb = blockIdx.z;
    int c0 = ccb * cper;
    int c1 = c0 + cper; if (c1 > Cin) c1 = Cin;
    int tid = threadIdx.x;
    int ocl = tid & 7, yq = (tid >> 3) & 15, xh = tid >> 7;
    int x = bx * 2 + xh;
    int oc = ocb * 8 + ocl;
    bool ocok = oc < Cout;
    v4f z4; z4.x = 0.f; z4.y = 0.f; z4.z = 0.f; z4.w = 0.f;

    const size_t wstep = (size_t)Cout * 4096;
    const float* wbase = Wt + (size_t)(ocok ? oc : 0) * 4096 + x * 64 + (yq << 2);

    // gload16 slots: LDS v4f v = tid + 256k, float f = 4v; window [bb][4][68]
    // maps to global channel offset bx*136 + (f % 272) within batch bb = f/272.
    int gbase[5];
#pragma unroll
    for (int k = 0; k < 5; ++k) {
        int f = 4 * tid + 1024 * k;
        int fv = (f < 4352) ? f : 0;
        int bb = fv / 272; int off = fv - bb * 272;
        gbase[k] = bb * (WC * 4488) + bx * 136 + off;
    }

    float acc[16][4];
#pragma unroll
    for (int bb = 0; bb < 16; ++bb)
#pragma unroll
        for (int k = 0; k < 4; ++k) acc[bb][k] = 0.f;

    // ---- prologue: stage A[c0] into sa[0]; weights for c0 ----
    {
        const float* src = Ac + (size_t)c0 * 4488;
#pragma unroll
        for (int k = 0; k < 4; ++k)
            gload16(src + gbase[k], &sa[0][4 * tid + 1024 * k]);
        if (tid < 64) gload16(src + gbase[4], &sa[0][4 * tid + 4096]);
    }
    v4f wvA[9];
#pragma unroll
    for (int t = 0; t < 9; ++t)
        wvA[t] = ocok ? __builtin_nontemporal_load(
                            (const v4f*)(wbase + ((size_t)c0 * 9 + t) * wstep))
                      : z4;
    __syncthreads();

    int cur = 0;
    for (int c = c0; c < c1; ++c) {
        bool hn = (c + 1) < c1;          // block-uniform
        v4f wvN[9];
        if (hn) {
            float* dst = sa[cur ^ 1];
            const float* src = Ac + (size_t)(c + 1) * 4488;
#pragma unroll
            for (int k = 0; k < 4; ++k)
                gload16(src + gbase[k], dst + 4 * tid + 1024 * k);
            if (tid < 64) gload16(src + gbase[4], dst + 4 * tid + 4096);
#pragma unroll
            for (int t = 0; t < 9; ++t)
                wvN[t] = ocok ? __builtin_nontemporal_load(
                                    (const v4f*)(wbase + ((size_t)(c + 1) * 9 + t) * wstep))
                              : z4;
        }
        const float* sab = sa[cur];
#pragma unroll
        for (int pi = 0; pi < 3; ++pi) {
#pragma unroll
            for (int bb = 0; bb < 16; ++bb) {
                const float* sp = &sab[(bb * 4 + xh + pi) * 68 + (yq << 2)];
                float4 s0 = *(const float4*)sp;
                float2 s1 = *(const float2*)(sp + 4);
                float sv[6] = {s0.x, s0.y, s0.z, s0.w, s1.x, s1.y};
#pragma unroll
                for (int k = 0; k < 4; ++k)
#pragma unroll
                    for (int pj = 0; pj < 3; ++pj)
                        acc[bb][k] = fmaf(sv[k + pj], wvA[pi * 3 + pj][k], acc[bb][k]);
            }
        }
        if (hn) {
            __syncthreads();             // drains gload_lds (vmcnt) + read hazard
#pragma unroll
            for (int t = 0; t < 9; ++t) wvA[t] = wvN[t];
            cur ^= 1;
        }
    }

    if (ocok) {
        float* Opc = Op + (size_t)ccb * ((size_t)NB * WC * 4096);
#pragma unroll
        for (int bb = 0; bb < 16; ++bb) {
            float4 o4;
            o4.x = acc[bb][0]; o4.y = acc[bb][1];
            o4.z = acc[bb][2]; o4.w = acc[bb][3];
            *(float4*)&Opc[(((size_t)bb * WC + oc) << 12) + x * 64 + (yq << 2)] = o4;
        }
    }
}

// ---------------- block update: xc = xc + gelu(conv1x1(xc)+bias + t1) ----------------
// v2: x-row hoisted to 64 VGPRs, LDS-staged weights read as broadcast b128
// (measured faster than wave-uniform global loads — round 4).
__global__ __launch_bounds__(256) void k_blockup(float* __restrict__ xc,
                                                 const float* __restrict__ sp,
                                                 const float* __restrict__ wmat,
                                                 const float* __restrict__ bias) {
    __shared__ float sw[64 * 64];
    __shared__ float sx[128 * 65];
    __shared__ float sb[64];
    int bi = blockIdx.x;          // b*128 + i
    int b = bi >> 7, i = bi & 127;
    int tid = threadIdx.x;
    for (int l = tid; l < 4096; l += 256) sw[l] = wmat[l];
    if (tid < 64) sb[tid] = bias[tid];
    for (int l = tid; l < 8192; l += 256) {
        int c = l >> 7, j = l & 127;
        sx[j * 65 + c] = xc[(((size_t)b * WC + c) << 14) + i * 128 + j];
    }
    __syncthreads();
    int j = tid & 127, h = tid >> 7;
    float xr[64];
#pragma unroll
    for (int c = 0; c < 64; ++c) xr[c] = sx[j * 65 + c];
#pragma unroll 2
    for (int o = 0; o < 32; ++o) {
        int oc = h * 32 + o;
        float a = sb[oc];
#pragma unroll
        for (int c4 = 0; c4 < 16; ++c4) {
            v4f w4 = *(const v4f*)&sw[oc * 64 + c4 * 4];
            a = fmaf(xr[c4 * 4 + 0], w4.x, a);
            a = fmaf(xr[c4 * 4 + 1], w4.y, a);
            a = fmaf(xr[c4 * 4 + 2], w4.z, a);
            a = fmaf(xr[c4 * 4 + 3], w4.w, a);
        }
        size_t gi = (((size_t)b * WC + oc) << 14) + i * 128 + j;
        float v = a + sp[gi];
        xc[gi] = sx[j * 65 + oc] + gelu_f(v);
    }
}

// ---------------- final MLP: out = (gelu(x@W1+b1))@W2 + b2 ----------------
// v2: x-row in registers, W1 staged transposed so the inner read is broadcast b128.
__global__ __launch_bounds__(256) void k_fc(const float* __restrict__ xc,
                                            const float* __restrict__ W1,
                                            const float* __restrict__ b1,
                                            const float* __restrict__ W2,
                                            const float* __restrict__ b2,
                                            float* __restrict__ out) {
    __shared__ float sW1T[128 * 68];   // [oo][c], 16B-aligned rows
    __shared__ float sx[128 * 65];
    __shared__ float sW2[128];
    __shared__ float sb1[128];
    __shared__ float spart[256];
    int bi = blockIdx.x; int b = bi >> 7, i = bi & 127;
    int tid = threadIdx.x;
    for (int l = tid; l < 8192; l += 256) {
        int c = l >> 7, oo = l & 127;
        sW1T[oo * 68 + c] = W1[l];
    }
    if (tid < 128) { sW2[tid] = W2[tid]; sb1[tid] = b1[tid]; }
    for (int l = tid; l < 8192; l += 256) {
        int c = l >> 7, j = l & 127;
        sx[j * 65 + c] = xc[(((size_t)b * WC + c) << 14) + i * 128 + j];
    }
    __syncthreads();
    int j = tid & 127, h = tid >> 7;
    float xr[64];
#pragma unroll
    for (int c = 0; c < 64; ++c) xr[c] = sx[j * 65 + c];
    float part = 0.f;
#pragma unroll 2
    for (int o = 0; o < 64; ++o) {
        int oo = h * 64 + o;
        float a = sb1[oo];
#pragma unroll
        for (int c4 = 0; c4 < 16; ++c4) {
            v4f w4 = *(const v4f*)&sW1T[oo * 68 + c4 * 4];
            a = fmaf(xr[c4 * 4 + 0], w4.x, a);
            a = fmaf(xr[c4 * 4 + 1], w4.y, a);
            a = fmaf(xr[c4 * 4 + 2], w4.z, a);
            a = fmaf(xr[c4 * 4 + 3], w4.w, a);
        }
        part += gelu_f(a) * sW2[oo];
    }
    spart[j * 2 + h] = part;
    __syncthreads();
    if (h == 0) out[(size_t)bi * 128 + j] = spart[j * 2] + spart[j * 2 + 1] + b2[0];
}

extern "C" void kernel_launch(void* const* d_in, const int* in_sizes, int n_in,
                              void* d_out, int out_size, void* d_ws, size_t ws_size,
                              hipStream_t stream) {
    (void)in_sizes; (void)n_in; (void)out_size; (void)ws_size;
    const float* x_in    = (const float*)d_in[0];
    const float* convl_w = (const float*)d_in[1];
    const float* conv_w[4] = {(const float*)d_in[2], (const float*)d_in[3],
                              (const float*)d_in[4], (const float*)d_in[5]};
    const float* ww[4] = {(const float*)d_in[6], (const float*)d_in[8],
                          (const float*)d_in[10], (const float*)d_in[12]};
    const float* wb[4] = {(const float*)d_in[7], (const float*)d_in[9],
                          (const float*)d_in[11], (const float*)d_in[13]};
    const float* fc1w = (const float*)d_in[14];
    const float* fc1b = (const float*)d_in[15];
    const float* fc2w = (const float*)d_in[16];
    const float* fc2b = (const float*)d_in[17];
    float* out = (float*)d_out;

    float* S   = (float*)d_ws;                       // 16384
    float* xc  = S + 16384;                          // 16.8M floats
    float* t1  = xc + (size_t)NB * WC * 16384;       // 16.8M floats
    float* tA  = t1 + (size_t)NB * WC * 16384;       // 4.60M floats (66x68-padded)
    float* Op  = tA + (size_t)NB * WC * 4488;        // 2 x 4.19M partials

    k_dst<<<64, 256, 0, stream>>>(S);
    k_tin<<<3072, 256, 0, stream>>>(x_in, xc);

    // lifting: u3 -> wswano(3 -> 61) -> gelu -> channels 3..63
    k_tfwd66<<<NB * 3, 256, 0, stream>>>(xc, tA, S, 3);
    k_mix6<<<dim3(32, 8, 1), 256, 0, stream>>>(tA, convl_w, Op, 3, 61, 3);
    k_tinv<<<NB * 61, 256, 0, stream>>>(Op, xc, S, 61, 1, 3, 1);

    for (int L = 0; L < 4; ++L) {
        k_tfwd66<<<NB * WC, 256, 0, stream>>>(xc, tA, S, WC);
        k_mix6<<<dim3(32, 8, 2), 256, 0, stream>>>(tA, conv_w[L], Op, WC, WC, 32);
        k_tinv<<<NB * WC, 256, 0, stream>>>(Op, t1, S, WC, 2, 0, 0);
        k_blockup<<<2048, 256, 0, stream>>>(xc, t1, ww[L], wb[L]);
    }

    k_fc<<<2048, 256, 0, stream>>>(xc, fc1w, fc1b, fc2w, fc2b, out);
}

// Round 16
// 1538.327 us; speedup vs baseline: 4.3988x; 1.0447x over previous
//
#include <hip/hip_runtime.h>
#include <math.h>

#define NB 16      // batch
#define NN 128     // spatial
#define WC 64      // width / channels
#define DD 64      // D1=D2
#define NP 66      // D + BW - 1

typedef float v4f __attribute__((ext_vector_type(4)));
typedef unsigned int u32;

__device__ __forceinline__ float gelu_f(float x) {
    return 0.5f * x * (1.0f + erff(x * 0.70710678118654752f));
}

// width-16 global->LDS direct copy (dest = wave-uniform base + lane*16)
__device__ __forceinline__ void gload16(const float* g, float* l) {
    __builtin_amdgcn_global_load_lds(
        (const __attribute__((address_space(1))) u32*)g,
        (__attribute__((address_space(3))) u32*)l, 16, 0, 0);
}

// ---------------- DST matrix ----------------
__global__ void k_dst(float* __restrict__ S) {
    int idx = blockIdx.x * 256 + threadIdx.x;   // 16384
    int k = idx >> 7, j = idx & 127;
    double arg = 3.14159265358979323846 * (double)((k + 1) * (j + 1)) / 129.0;
    S[idx] = (float)(sqrt(2.0 / 129.0) * sin(arg));
}

// ---------------- transpose input (B,N,N,3) -> (B,64ch,N,N) ch0..2 ----------------
__global__ void k_tin(const float* __restrict__ in, float* __restrict__ xc) {
    int idx = blockIdx.x * 256 + threadIdx.x;   // 16*3*16384
    int j = idx & 127;
    int i = (idx >> 7) & 127;
    int t = idx >> 14;           // b*3 + c
    int b = t / 3, c = t - b * 3;
    xc[(((size_t)b * WC + c) << 14) + i * 128 + j] =
        in[((size_t)(b * 128 + i) * 128 + j) * 3 + c];
}

// ---------------- forward transform, compact 66x(68-padded) output ----------------
// v3: DST parity fold (S[k][127-j] = (-1)^k S[k][j]) applied to BOTH stages,
// redesigned after round-3's raced attempt using the (replay-proven) tinv-v5
// discipline: FIVE disjoint LDS buffers (no aliasing/repurposing), uniform
// barrier skeleton, owner-exclusive barrier-separated RMW for the T fold:
//   stage1: T[row][k] = sum_{j<64} S[k][j]*(Xe|Xo)[row][j]   (parity of k)
//   T fold: Te[m][i] = T[i][m]+T[127-i][m], To = difference  (i<64)
//   stage2: A[kk][m] = sum_{i<64} S[kk][i]*(Te|To)[m][i]     (parity of kk)
// FMA & stage-2 LDS reads halve; per-thread LDS ops 776->568. LDS 88.7 KB
// -> 1 block/CU (4 waves; LDS pipe is throughput-bound so acceptable).
// OOB k/m: clamped load address + write guard (results discarded, v1 style).
__global__ __launch_bounds__(256, 1) void k_tfwd66(const float* __restrict__ Xg,
                                                   float* __restrict__ Yc,
                                                   const float* __restrict__ Sg,
                                                   int Cact) {
    __shared__ float sS[66 * 68];    // S[k][j], k<66, j<64
    __shared__ float sXe[64 * 68];   // even fold of X, current 64-row half
    __shared__ float sXo[64 * 68];   // odd fold
    __shared__ float sTe[66 * 68];   // Te[m][i]
    __shared__ float sTo[66 * 68];   // To[m][i]
    int bid = blockIdx.x;
    int b = bid / Cact, c = bid - b * Cact;
    const float* X = Xg + (((size_t)b * WC + c) << 14);
    int tid = threadIdx.x;
    int tx = tid & 15, ty = tid >> 4;
    // stage S rows 0..65, cols 0..63 (visible at first in-loop barrier)
    for (int l = tid; l < 66 * 64; l += 256)
        sS[(l >> 6) * 68 + (l & 63)] = Sg[((l >> 6) << 7) + (l & 63)];
    const float* xb = (tx & 1) ? sXo : sXe;   // k = tx+16q: parity = parity(tx)
    for (int h = 0; h < 2; ++h) {
        __syncthreads();   // prior half's sXe/sXo reads + h0 Te/To writes ordered
        for (int l = tid; l < 4096; l += 256) {
            int row = l >> 6, j = l & 63;
            const float* xr = X + ((h * 64 + row) << 7);
            float x0 = xr[j], x1 = xr[127 - j];
            sXe[row * 68 + j] = x0 + x1;
            sXo[row * 68 + j] = x0 - x1;
        }
        __syncthreads();
        float acc[4][5];
#pragma unroll
        for (int r = 0; r < 4; ++r)
#pragma unroll
            for (int q = 0; q < 5; ++q) acc[r][q] = 0.f;
        for (int jj = 0; jj < 64; jj += 4) {
            float4 xv[4], sv[5];
#pragma unroll
            for (int r = 0; r < 4; ++r)
                xv[r] = *(const float4*)&xb[(ty + 16 * r) * 68 + jj];
#pragma unroll
            for (int q = 0; q < 5; ++q) {
                int k = tx + 16 * q;
                int kc = (k < 66) ? k : 65;   // clamp: result discarded for k>=66
                sv[q] = *(const float4*)&sS[kc * 68 + jj];
            }
#pragma unroll
            for (int r = 0; r < 4; ++r)
#pragma unroll
                for (int q = 0; q < 5; ++q) {
                    acc[r][q] += xv[r].x * sv[q].x;
                    acc[r][q] += xv[r].y * sv[q].y;
                    acc[r][q] += xv[r].z * sv[q].z;
                    acc[r][q] += xv[r].w * sv[q].w;
                }
        }
        // fold-write T: slot (k,i) owned by exactly one thread per half;
        // h1's RMW reads h0's writes across the top-of-loop barrier.
        if (h == 0) {
#pragma unroll
            for (int q = 0; q < 5; ++q) {
                int k = tx + 16 * q;
                if (k < 66) {
#pragma unroll
                    for (int r = 0; r < 4; ++r) {
                        int i = ty + 16 * r;
                        float v = acc[r][q];
                        sTe[k * 68 + i] = v;
                        sTo[k * 68 + i] = v;
                    }
                }
            }
        } else {
#pragma unroll
            for (int q = 0; q < 5; ++q) {
                int k = tx + 16 * q;
                if (k < 66) {
#pragma unroll
                    for (int r = 0; r < 4; ++r) {
                        int i = 63 - (ty + 16 * r);   // mirror of row 64+ty+16r
                        float v = acc[r][q];
                        sTe[k * 68 + i] += v;
                        sTo[k * 68 + i] -= v;
                    }
                }
            }
        }
    }
    __syncthreads();   // all Te/To visible
    // stage 2: kk = ty+16r (parity = parity(ty)), m = tx+16q
    const float* tb = (ty & 1) ? sTo : sTe;
    float a2[5][5];
#pragma unroll
    for (int r = 0; r < 5; ++r)
#pragma unroll
        for (int q = 0; q < 5; ++q) a2[r][q] = 0.f;
    for (int i0 = 0; i0 < 64; i0 += 4) {
        float4 sv[5], tv[5];
#pragma unroll
        for (int r = 0; r < 5; ++r) {
            int kk = ty + 16 * r;
            int kc = (kk < 66) ? kk : 65;
            sv[r] = *(const float4*)&sS[kc * 68 + i0];
        }
#pragma unroll
        for (int q = 0; q < 5; ++q) {
            int m = tx + 16 * q;
            int mc = (m < 66) ? m : 65;
            tv[q] = *(const float4*)&tb[mc * 68 + i0];
        }
#pragma unroll
        for (int r = 0; r < 5; ++r)
#pragma unroll
            for (int q = 0; q < 5; ++q) {
                a2[r][q] += sv[r].x * tv[q].x;
                a2[r][q] += sv[r].y * tv[q].y;
                a2[r][q] += sv[r].z * tv[q].z;
                a2[r][q] += sv[r].w * tv[q].w;
            }
    }
    float* Y = Yc + (size_t)(b * WC + c) * 4488;    // 66 rows x 68-stride
#pragma unroll
    for (int r = 0; r < 5; ++r) {
        int kk = ty + 16 * r;
        if (kk < 66) {
#pragma unroll
            for (int q = 0; q < 5; ++q) {
                int m = tx + 16 * q;
                if (m < 66) Y[kk * 68 + m] = a2[r][q];
            }
        }
    }
}

// ---------------- inverse transform + partial-sum + optional gelu/ch-offset ----------
// v5: DST parity fold on OUTPUT cols (stage 1) and OUTPUT rows (stage 2).
// FMA 6144->3072, LDS reads 704->512, sS 16KB -> 3 blocks/CU. (round-10 win)
__global__ __launch_bounds__(256, 3) void k_tinv(const float* __restrict__ Op,
                                                 float* __restrict__ Yg,
                                                 const float* __restrict__ Sg,
                                                 int Cact, int ncc, int ch_off, int do_gelu) {
    __shared__ float sS[64 * 64];      // S rows 0..63, cols 0..63 (16 KB)
    __shared__ float sXT[64 * 132];    // union: X (stride 66) then T (stride 132)
    int bid = blockIdx.x;
    int b = bid / Cact, c = bid - b * Cact;
    const float* X = Op + ((size_t)(b * WC + c) << 12);
    const size_t cstride = (size_t)NB * WC * 4096;
    float* Y = Yg + (((size_t)b * WC + c + ch_off) << 14);
    int tid = threadIdx.x;
    for (int l = tid; l < 4096; l += 256)
        sS[l] = Sg[((l >> 6) << 7) + (l & 63)];
    for (int l = tid; l < 4096; l += 256) {
        int r = l >> 6, q = l & 63;
        float v = X[l];
        for (int cc = 1; cc < ncc; ++cc) v += X[cc * cstride + l];
        sXT[r * 66 + q] = v;            // stride 66: b64-aligned pair reads later
    }
    __syncthreads();
    int cg = tid & 7;
    int rg = tid >> 3;                  // 0..31
    // ---- stage 1 (col-fold): P/M over even/odd j, cols c = cg*4+32m' (m'<2) ----
    v4f aP[2][2], aM[2][2];
#pragma unroll
    for (int r = 0; r < 2; ++r)
#pragma unroll
        for (int m = 0; m < 2; ++m) {
            aP[r][m].x = 0.f; aP[r][m].y = 0.f; aP[r][m].z = 0.f; aP[r][m].w = 0.f;
            aM[r][m].x = 0.f; aM[r][m].y = 0.f; aM[r][m].z = 0.f; aM[r][m].w = 0.f;
        }
    for (int jp = 0; jp < 32; ++jp) {
        float2 x0 = *(const float2*)&sXT[(rg * 2 + 0) * 66 + 2 * jp];
        float2 x1 = *(const float2*)&sXT[(rg * 2 + 1) * 66 + 2 * jp];
#pragma unroll
        for (int m = 0; m < 2; ++m) {
            v4f se = *(const v4f*)&sS[(2 * jp) * 64 + cg * 4 + 32 * m];
            v4f so = *(const v4f*)&sS[(2 * jp + 1) * 64 + cg * 4 + 32 * m];
            aP[0][m] += se * x0.x;  aM[0][m] += so * x0.y;
            aP[1][m] += se * x1.x;  aM[1][m] += so * x1.y;
        }
    }
    __syncthreads();                    // all X reads done; reuse buffer for T
#pragma unroll
    for (int r = 0; r < 2; ++r)
#pragma unroll
        for (int m = 0; m < 2; ++m) {
            v4f tlo = aP[r][m] + aM[r][m];
            v4f td  = aP[r][m] - aM[r][m];
            v4f thi; thi.x = td.w; thi.y = td.z; thi.z = td.y; thi.w = td.x;
            int row = rg * 2 + r;
            *(v4f*)&sXT[row * 132 + cg * 4 + 32 * m] = tlo;
            *(v4f*)&sXT[row * 132 + 124 - cg * 4 - 32 * m] = thi;
        }
    __syncthreads();
    // ---- stage 2 (row-fold): P/M over even/odd i; rows rg*2+r and 127-(rg*2+r) ----
    v4f p2[2][4], m2[2][4];
#pragma unroll
    for (int r = 0; r < 2; ++r)
#pragma unroll
        for (int m = 0; m < 4; ++m) {
            p2[r][m].x = 0.f; p2[r][m].y = 0.f; p2[r][m].z = 0.f; p2[r][m].w = 0.f;
            m2[r][m].x = 0.f; m2[r][m].y = 0.f; m2[r][m].z = 0.f; m2[r][m].w = 0.f;
        }
    for (int ip = 0; ip < 32; ++ip) {
        float2 sve = *(const float2*)&sS[(2 * ip) * 64 + rg * 2];
        float2 svo = *(const float2*)&sS[(2 * ip + 1) * 64 + rg * 2];
#pragma unroll
        for (int m = 0; m < 4; ++m) {
            v4f te = *(const v4f*)&sXT[(2 * ip) * 132 + cg * 4 + 32 * m];
            v4f to = *(const v4f*)&sXT[(2 * ip + 1) * 132 + cg * 4 + 32 * m];
            p2[0][m] += te * sve.x;  p2[1][m] += te * sve.y;
            m2[0][m] += to * svo.x;  m2[1][m] += to * svo.y;
        }
    }
#pragma unroll
    for (int r = 0; r < 2; ++r) {
        int rlo = rg * 2 + r, rhi = 127 - rlo;
#pragma unroll
        for (int m = 0; m < 4; ++m) {
            v4f ylo = p2[r][m] + m2[r][m];
            v4f yhi = p2[r][m] - m2[r][m];
            if (do_gelu) {
                ylo.x = gelu_f(ylo.x); ylo.y = gelu_f(ylo.y);
                ylo.z = gelu_f(ylo.z); ylo.w = gelu_f(ylo.w);
                yhi.x = gelu_f(yhi.x); yhi.y = gelu_f(yhi.y);
                yhi.z = gelu_f(yhi.z); yhi.w = gelu_f(yhi.w);
            }
            *(v4f*)&Y[rlo * 128 + cg * 4 + 32 * m] = ylo;
            *(v4f*)&Y[rhi * 128 + cg * 4 + 32 * m] = yhi;
        }
    }
}

// ---------------- spectral channel mixing v4 (FINAL — round-7 known-good) ----------------
// Thread map: (ocl 0..7, yq 0..15, xh 0..1); block covers 2 x-rows; thread owns
// all 16 batches -> every thread's 9 weight loads are UNIQUE. A staged via
// width-16 global_load_lds ([bb][4][68] windows, tA rows 68-padded).
// 1-deep weight prefetch, 1 barrier/c. ~180 VGPR, 2 blocks/CU.
// [CLOSED after 4 spill failures (r8/r11/r13/r14): any 2-oc widening
//  (acc 128) or weight-lifetime pinning overflows the 256-VGPR/wave arch cap
//  and spills to scratch. The compiler's freedom to sink prefetch loads is
//  what keeps v4 spill-free.]
__global__ __launch_bounds__(256, 2) void k_mix6(const float* __restrict__ Ac,
                                                 const float* __restrict__ Wt,
                                                 float* __restrict__ Op,
                                                 int Cin, int Cout, int cper) {
    __shared__ __align__(16) float sa[2][16 * 4 * 68];   // 2 x 4352 floats
    int bx = blockIdx.x;         // 0..31 (x pair)
    int ocb = blockIdx.y;        // 0..7
    int ccb = blockIdx.z;
    int c0 = ccb * cper;
    int c1 = c0 + cper; if (c1 > Cin) c1 = Cin;
    int tid = threadIdx.x;
    int ocl = tid & 7, yq = (tid >> 3) & 15, xh = tid >> 7;
    int x = bx * 2 + xh;
    int oc = ocb * 8 + ocl;
    bool ocok = oc < Cout;
    v4f z4; z4.x = 0.f; z4.y = 0.f; z4.z = 0.f; z4.w = 0.f;

    const size_t wstep = (size_t)Cout * 4096;
    const float* wbase = Wt + (size_t)(ocok ? oc : 0) * 4096 + x * 64 + (yq << 2);

    // gload16 slots: LDS v4f v = tid + 256k, float f = 4v; window [bb][4][68]
    // maps to global channel offset bx*136 + (f % 272) within batch bb = f/272.
    int gbase[5];
#pragma unroll
    for (int k = 0; k < 5; ++k) {
        int f = 4 * tid + 1024 * k;
        int fv = (f < 4352) ? f : 0;
        int bb = fv / 272; int off = fv - bb * 272;
        gbase[k] = bb * (WC * 4488) + bx * 136 + off;
    }

    float acc[16][4];
#pragma unroll
    for (int bb = 0; bb < 16; ++bb)
#pragma unroll
        for (int k = 0; k < 4; ++k) acc[bb][k] = 0.f;

    // ---- prologue: stage A[c0] into sa[0]; weights for c0 ----
    {
        const float* src = Ac + (size_t)c0 * 4488;
#pragma unroll
        for (int k = 0; k < 4; ++k)
            gload16(src + gbase[k], &sa[0][4 * tid + 1024 * k]);
        if (tid < 64) gload16(src + gbase[4], &sa[0][4 * tid + 4096]);
    }
    v4f wvA[9];
#pragma unroll
    for (int t = 0; t < 9; ++t)
        wvA[t] = ocok ? __builtin_nontemporal_load(
                            (const v4f*)(wbase + ((size_t)c0 * 9 + t) * wstep))
                      : z4;
    __syncthreads();

    int cur = 0;
    for (int c = c0; c < c1; ++c) {
        bool hn = (c + 1) < c1;          // block-uniform
        v4f wvN[9];
        if (hn) {
            float* dst = sa[cur ^ 1];
            const float* src = Ac + (size_t)(c + 1) * 4488;
#pragma unroll
            for (int k = 0; k < 4; ++k)
                gload16(src + gbase[k], dst + 4 * tid + 1024 * k);
            if (tid < 64) gload16(src + gbase[4], dst + 4 * tid + 4096);
#pragma unroll
            for (int t = 0; t < 9; ++t)
                wvN[t] = ocok ? __builtin_nontemporal_load(
                                    (const v4f*)(wbase + ((size_t)(c + 1) * 9 + t) * wstep))
                              : z4;
        }
        const float* sab = sa[cur];
#pragma unroll
        for (int pi = 0; pi < 3; ++pi) {
#pragma unroll
            for (int bb = 0; bb < 16; ++bb) {
                const float* sp = &sab[(bb * 4 + xh + pi) * 68 + (yq << 2)];
                float4 s0 = *(const float4*)sp;
                float2 s1 = *(const float2*)(sp + 4);
                float sv[6] = {s0.x, s0.y, s0.z, s0.w, s1.x, s1.y};
#pragma unroll
                for (int k = 0; k < 4; ++k)
#pragma unroll
                    for (int pj = 0; pj < 3; ++pj)
                        acc[bb][k] = fmaf(sv[k + pj], wvA[pi * 3 + pj][k], acc[bb][k]);
            }
        }
        if (hn) {
            __syncthreads();             // drains gload_lds (vmcnt) + read hazard
#pragma unroll
            for (int t = 0; t < 9; ++t) wvA[t] = wvN[t];
            cur ^= 1;
        }
    }

    if (ocok) {
        float* Opc = Op + (size_t)ccb * ((size_t)NB * WC * 4096);
#pragma unroll
        for (int bb = 0; bb < 16; ++bb) {
            float4 o4;
            o4.x = acc[bb][0]; o4.y = acc[bb][1];
            o4.z = acc[bb][2]; o4.w = acc[bb][3];
            *(float4*)&Opc[(((size_t)bb * WC + oc) << 12) + x * 64 + (yq << 2)] = o4;
        }
    }
}

// ---------------- block update: xc = xc + gelu(conv1x1(xc)+bias + t1) ----------------
// v2: x-row hoisted to 64 VGPRs, LDS-staged weights read as broadcast b128
// (measured faster than wave-uniform global loads — round 4).
__global__ __launch_bounds__(256) void k_blockup(float* __restrict__ xc,
                                                 const float* __restrict__ sp,
                                                 const float* __restrict__ wmat,
                                                 const float* __restrict__ bias) {
    __shared__ float sw[64 * 64];
    __shared__ float sx[128 * 65];
    __shared__ float sb[64];
    int bi = blockIdx.x;          // b*128 + i
    int b = bi >> 7, i = bi & 127;
    int tid = threadIdx.x;
    for (int l = tid; l < 4096; l += 256) sw[l] = wmat[l];
    if (tid < 64) sb[tid] = bias[tid];
    for (int l = tid; l < 8192; l += 256) {
        int c = l >> 7, j = l & 127;
        sx[j * 65 + c] = xc[(((size_t)b * WC + c) << 14) + i * 128 + j];
    }
    __syncthreads();
    int j = tid & 127, h = tid >> 7;
    float xr[64];
#pragma unroll
    for (int c = 0; c < 64; ++c) xr[c] = sx[j * 65 + c];
#pragma unroll 2
    for (int o = 0; o < 32; ++o) {
        int oc = h * 32 + o;
        float a = sb[oc];
#pragma unroll
        for (int c4 = 0; c4 < 16; ++c4) {
            v4f w4 = *(const v4f*)&sw[oc * 64 + c4 * 4];
            a = fmaf(xr[c4 * 4 + 0], w4.x, a);
            a = fmaf(xr[c4 * 4 + 1], w4.y, a);
            a = fmaf(xr[c4 * 4 + 2], w4.z, a);
            a = fmaf(xr[c4 * 4 + 3], w4.w, a);
        }
        size_t gi = (((size_t)b * WC + oc) << 14) + i * 128 + j;
        float v = a + sp[gi];
        xc[gi] = sx[j * 65 + oc] + gelu_f(v);
    }
}

// ---------------- final MLP: out = (gelu(x@W1+b1))@W2 + b2 ----------------
// v2: x-row in registers, W1 staged transposed so the inner read is broadcast b128.
__global__ __launch_bounds__(256) void k_fc(const float* __restrict__ xc,
                                            const float* __restrict__ W1,
                                            const float* __restrict__ b1,
                                            const float* __restrict__ W2,
                                            const float* __restrict__ b2,
                                            float* __restrict__ out) {
    __shared__ float sW1T[128 * 68];   // [oo][c], 16B-aligned rows
    __shared__ float sx[128 * 65];
    __shared__ float sW2[128];
    __shared__ float sb1[128];
    __shared__ float spart[256];
    int bi = blockIdx.x; int b = bi >> 7, i = bi & 127;
    int tid = threadIdx.x;
    for (int l = tid; l < 8192; l += 256) {
        int c = l >> 7, oo = l & 127;
        sW1T[oo * 68 + c] = W1[l];
    }
    if (tid < 128) { sW2[tid] = W2[tid]; sb1[tid] = b1[tid]; }
    for (int l = tid; l < 8192; l += 256) {
        int c = l >> 7, j = l & 127;
        sx[j * 65 + c] = xc[(((size_t)b * WC + c) << 14) + i * 128 + j];
    }
    __syncthreads();
    int j = tid & 127, h = tid >> 7;
    float xr[64];
#pragma unroll
    for (int c = 0; c < 64; ++c) xr[c] = sx[j * 65 + c];
    float part = 0.f;
#pragma unroll 2
    for (int o = 0; o < 64; ++o) {
        int oo = h * 64 + o;
        float a = sb1[oo];
#pragma unroll
        for (int c4 = 0; c4 < 16; ++c4) {
            v4f w4 = *(const v4f*)&sW1T[oo * 68 + c4 * 4];
            a = fmaf(xr[c4 * 4 + 0], w4.x, a);
            a = fmaf(xr[c4 * 4 + 1], w4.y, a);
            a = fmaf(xr[c4 * 4 + 2], w4.z, a);
            a = fmaf(xr[c4 * 4 + 3], w4.w, a);
        }
        part += gelu_f(a) * sW2[oo];
    }
    spart[j * 2 + h] = part;
    __syncthreads();
    if (h == 0) out[(size_t)bi * 128 + j] = spart[j * 2] + spart[j * 2 + 1] + b2[0];
}

extern "C" void kernel_launch(void* const* d_in, const int* in_sizes, int n_in,
                              void* d_out, int out_size, void* d_ws, size_t ws_size,
                              hipStream_t stream) {
    (void)in_sizes; (void)n_in; (void)out_size; (void)ws_size;
    const float* x_in    = (const float*)d_in[0];
    const float* convl_w = (const float*)d_in[1];
    const float* conv_w[4] = {(const float*)d_in[2], (const float*)d_in[3],
                              (const float*)d_in[4], (const float*)d_in[5]};
    const float* ww[4] = {(const float*)d_in[6], (const float*)d_in[8],
                          (const float*)d_in[10], (const float*)d_in[12]};
    const float* wb[4] = {(const float*)d_in[7], (const float*)d_in[9],
                          (const float*)d_in[11], (const float*)d_in[13]};
    const float* fc1w = (const float*)d_in[14];
    const float* fc1b = (const float*)d_in[15];
    const float* fc2w = (const float*)d_in[16];
    const float* fc2b = (const float*)d_in[17];
    float* out = (float*)d_out;

    float* S   = (float*)d_ws;                       // 16384
    float* xc  = S + 16384;                          // 16.8M floats
    float* t1  = xc + (size_t)NB * WC * 16384;       // 16.8M floats
    float* tA  = t1 + (size_t)NB * WC * 16384;       // 4.60M floats (66x68-padded)
    float* Op  = tA + (size_t)NB * WC * 4488;        // 2 x 4.19M partials

    k_dst<<<64, 256, 0, stream>>>(S);
    k_tin<<<3072, 256, 0, stream>>>(x_in, xc);

    // lifting: u3 -> wswano(3 -> 61) -> gelu -> channels 3..63
    k_tfwd66<<<NB * 3, 256, 0, stream>>>(xc, tA, S, 3);
    k_mix6<<<dim3(32, 8, 1), 256, 0, stream>>>(tA, convl_w, Op, 3, 61, 3);
    k_tinv<<<NB * 61, 256, 0, stream>>>(Op, xc, S, 61, 1, 3, 1);

    for (int L = 0; L < 4; ++L) {
        k_tfwd66<<<NB * WC, 256, 0, stream>>>(xc, tA, S, WC);
        k_mix6<<<dim3(32, 8, 2), 256, 0, stream>>>(tA, conv_w[L], Op, WC, WC, 32);
        k_tinv<<<NB * WC, 256, 0, stream>>>(Op, t1, S, WC, 2, 0, 0);
        k_blockup<<<2048, 256, 0, stream>>>(xc, t1, ww[L], wb[L]);
    }

    k_fc<<<2048, 256, 0, stream>>>(xc, fc1w, fc1b, fc2w, fc2b, out);
}